// Round 4
// baseline (318.672 us; speedup 1.0000x reference)
//
#include <hip/hip_runtime.h>

typedef unsigned short u16;
typedef __bf16 bf16x8 __attribute__((ext_vector_type(8)));
typedef float floatx4 __attribute__((ext_vector_type(4)));

__device__ __forceinline__ u16 f2bf(float f) {
    unsigned u = __float_as_uint(f);
    u += 0x7fff + ((u >> 16) & 1);   // round-to-nearest-even
    return (u16)(u >> 16);
}

#define GLOAD_LDS16(g, l) __builtin_amdgcn_global_load_lds( \
    (const __attribute__((address_space(1))) void*)(g),      \
    (__attribute__((address_space(3))) void*)(l), 16, 0, 0)

// ---------------- cast x fp32 -> bf16, copy-ubench shape: 2x float4 in, 1x uint4 out ----------------
__global__ __launch_bounds__(256) void cast_x_kernel(
    const float* __restrict__ x, u16* __restrict__ x_bf)
{
    const int tid = threadIdx.x;
    const size_t base = (size_t)blockIdx.x * 1024 + tid;   // uint4 units
    const float4* src = (const float4*)x;
    uint4* dst = (uint4*)x_bf;
    float4 a[4], b[4];
    #pragma unroll
    for (int i = 0; i < 4; ++i) {
        a[i] = src[(base + i * 256) * 2];
        b[i] = src[(base + i * 256) * 2 + 1];
    }
    #pragma unroll
    for (int i = 0; i < 4; ++i) {
        uint4 o;
        o.x = (unsigned)f2bf(a[i].x) | ((unsigned)f2bf(a[i].y) << 16);
        o.y = (unsigned)f2bf(a[i].z) | ((unsigned)f2bf(a[i].w) << 16);
        o.z = (unsigned)f2bf(b[i].x) | ((unsigned)f2bf(b[i].y) << 16);
        o.w = (unsigned)f2bf(b[i].z) | ((unsigned)f2bf(b[i].w) << 16);
        dst[base + i * 256] = o;
    }
}

// ---------------- transposes: conv_w (blocks 0..2047) + small weights (2048..3071) ----------------
__global__ __launch_bounds__(256) void prep2_kernel(
    const float* __restrict__ conv_w, u16* __restrict__ WconvT,
    const float* __restrict__ Wq, u16* __restrict__ WqTp,
    const float* __restrict__ Wp, u16* __restrict__ WpT,
    const float* __restrict__ Wkv, u16* __restrict__ WkvT)
{
    int blk = blockIdx.x;
    const int tid = threadIdx.x;
    __shared__ __align__(16) char smem[16896];

    if (blk < 2048) {
        // conv_w [32768 k][512 cout] fp32 -> WconvT [512 cout][32768 k] bf16
        // tile: 64 couts x 128 k. LDS staged bf16 [128 k][66 cout] (pitch 66 u16).
        u16 (*T)[66] = (u16(*)[66])smem;
        const int by = blk >> 8;        // 0..7   cout chunk
        const int bx = blk & 255;       // 0..255 k chunk
        const int c0 = by * 64, k0 = bx * 128;
        const int f = tid & 15, kl = tid >> 4;
        #pragma unroll
        for (int it = 0; it < 8; ++it) {
            int k = kl + it * 16;
            float4 v = *(const float4*)(conv_w + (size_t)(k0 + k) * 512 + c0 + f * 4);
            *(unsigned*)&T[k][f * 4]     = (unsigned)f2bf(v.x) | ((unsigned)f2bf(v.y) << 16);
            *(unsigned*)&T[k][f * 4 + 2] = (unsigned)f2bf(v.z) | ((unsigned)f2bf(v.w) << 16);
        }
        __syncthreads();
        const int cl = tid >> 6, p = tid & 63;
        #pragma unroll
        for (int it = 0; it < 16; ++it) {
            int c = cl + it * 4;
            unsigned lo = T[p * 2][c], hi = T[p * 2 + 1][c];
            // one full 256 B contiguous row segment per wave
            *(unsigned*)&WconvT[(size_t)(c0 + c) * 32768 + k0 + p * 2] = lo | (hi << 16);
        }
        return;
    }
    blk -= 2048;

    const float* in; u16* outp; int R, Cn, bx, by; bool perm = false;
    if (blk < 256)      { in = Wq;  outp = WqTp; R = 512; Cn = 512;  bx = blk & 15; by = blk >> 4; perm = true; }
    else if (blk < 512) { blk -= 256; in = Wp;  outp = WpT;  R = 512; Cn = 512;  bx = blk & 15; by = blk >> 4; }
    else                { blk -= 512; in = Wkv; outp = WkvT; R = 512; Cn = 1024; bx = blk & 31; by = blk >> 5; }
    float (*tile)[33] = (float(*)[33])smem;
    const int c0 = bx * 32, r0 = by * 32;
    const int tx = tid & 31, ty = tid >> 5;
    #pragma unroll
    for (int yy = 0; yy < 4; ++yy)
        tile[ty + yy * 8][tx] = in[(size_t)(r0 + ty + yy * 8) * Cn + c0 + tx];
    __syncthreads();
    #pragma unroll
    for (int yy = 0; yy < 4; ++yy) {
        int cc = c0 + ty + yy * 8;
        int np = perm ? ((cc & 7) * 64 + (cc >> 3)) : cc;
        outp[(size_t)np * R + r0 + tx] = f2bf(tile[tx][ty + yy * 8]);
    }
}

// ---------------- MFMA GEMM: C[M,N] = A[M,K] * B^T[N,K]  (bf16 in, fp32 acc) ----------------
// BK=64 staged as two [128][32] sub-tiles per operand (keeps 64B LDS row stride).
// ASRC 0: A is plain [M,K] bf16.  ASRC 1: A rows are conv patches gathered from x_bf.
// MODE 0: split-K partial store bf16  ((u16*)out)[z*262144 + m*512 + n]   (conv fmap)
// MODE 1: q store (B cols pre-permuted head-major): h=n>>6, d=n&63 -> q_bf[(b*8+h)*4096+nn][d]
// MODE 2: kv permute (plain store)  K: kv[(b*8+h)*64+m][d]; V transposed: kv[V + (b*8+h)*64+d][m]
// MODE 3: out + bias  -> d_out[M,512] fp32
// MODE != 0: XCD-chunked block swizzle (blocks sharing an A panel land on one XCD's L2)
template<int MODE, int ASRC>
__global__ __launch_bounds__(256) void gemm_bt(
    const u16* __restrict__ A, const u16* __restrict__ B, float* __restrict__ out,
    int M, int N, int K, int KC, const float* __restrict__ bias)
{
    __shared__ u16 As[2][128 * 32];
    __shared__ u16 Bs[2][128 * 32];
    const int tid = threadIdx.x;
    const int wv = tid >> 6, lane = tid & 63;
    const int quad = lane >> 4, l15 = lane & 15;

    constexpr int GX = (MODE == 2) ? 8 : 4;
    int id = blockIdx.y * GX + blockIdx.x;
    if (MODE != 0) {
        const int nwg = GX * gridDim.y;          // divisible by 8 for all uses
        id = (id & 7) * (nwg >> 3) + (id >> 3);  // bijective chunked XCD swizzle
    }
    const int bm = (id / GX) * 128, bn = (id % GX) * 128;
    const int k0 = blockIdx.z * KC;
    const int wr = wv >> 1, wc = wv & 1;

    floatx4 acc[4][4];
    #pragma unroll
    for (int i = 0; i < 4; ++i)
        #pragma unroll
        for (int j = 0; j < 4; ++j)
            acc[i][j] = (floatx4){0.f, 0.f, 0.f, 0.f};

    for (int kt = 0; kt < KC; kt += 64) {
        const int kk = k0 + kt;
        #pragma unroll
        for (int hf = 0; hf < 2; ++hf) {
            #pragma unroll
            for (int c2 = 0; c2 < 2; ++c2) {
                int idx = ((wv * 2 + c2) * 64 + lane) * 8;   // element offset in [128][32] half
                int row = idx >> 5, col = idx & 31;
                int k = kk + hf * 32 + col;
                if (ASRC == 0) {
                    const u16* ga = A + (size_t)(bm + row) * K + k;
                    GLOAD_LDS16(ga, &As[hf][(wv * 2 + c2) * 512]);
                } else {
                    // conv patch gather: row p=(b,ii,jj), k=(r1,r2,cin)
                    int p = bm + row;
                    int b = p >> 6, ij = p & 63, ii = ij >> 3, jj = ij & 7;
                    int r12 = k >> 9, r1 = r12 >> 3, r2 = r12 & 7;
                    int n = (ii * 8 + r1) * 64 + jj * 8 + r2;
                    const u16* ga = A + ((size_t)(b * 4096 + n)) * 512 + (k & 511);
                    GLOAD_LDS16(ga, &As[hf][(wv * 2 + c2) * 512]);
                }
                const u16* gb = B + (size_t)(bn + row) * K + k;
                GLOAD_LDS16(gb, &Bs[hf][(wv * 2 + c2) * 512]);
            }
        }
        __syncthreads();
        #pragma unroll
        for (int ks = 0; ks < 2; ++ks) {
            bf16x8 af[4], bfr[4];
            #pragma unroll
            for (int i = 0; i < 4; ++i)
                af[i] = *(const bf16x8*)&As[ks][(wr * 64 + i * 16 + l15) * 32 + quad * 8];
            #pragma unroll
            for (int j = 0; j < 4; ++j)
                bfr[j] = *(const bf16x8*)&Bs[ks][(wc * 64 + j * 16 + l15) * 32 + quad * 8];
            #pragma unroll
            for (int i = 0; i < 4; ++i)
                #pragma unroll
                for (int j = 0; j < 4; ++j)
                    acc[i][j] = __builtin_amdgcn_mfma_f32_16x16x32_bf16(af[i], bfr[j], acc[i][j], 0, 0, 0);
        }
        __syncthreads();
    }

    #pragma unroll
    for (int i = 0; i < 4; ++i) {
        #pragma unroll
        for (int j = 0; j < 4; ++j) {
            #pragma unroll
            for (int r = 0; r < 4; ++r) {
                int m = bm + wr * 64 + i * 16 + quad * 4 + r;
                int n = bn + wc * 64 + j * 16 + l15;
                float v = acc[i][j][r];
                if (MODE == 0) {
                    ((u16*)out)[(size_t)blockIdx.z * 262144 + (size_t)m * N + n] = f2bf(v);
                } else if (MODE == 1) {
                    int b = m >> 12, nn = m & 4095;
                    int h = n >> 6, d = n & 63;     // B columns pre-permuted head-major
                    ((u16*)out)[((size_t)((b * 8 + h) * 4096 + nn)) * 64 + d] = f2bf(v);
                } else if (MODE == 2) {
                    int b = m >> 6, mm = m & 63;
                    int f = n >> 9, c = n & 511, h = c >> 6, d = c & 63;
                    size_t idx;
                    if (f == 0) idx = ((size_t)((b * 8 + h) * 64 + mm)) * 64 + d;
                    else        idx = 262144 + ((size_t)((b * 8 + h) * 64 + d)) * 64 + mm;  // V^T
                    out[idx] = v;
                } else {
                    out[(size_t)m * 512 + n] = v + bias[n];
                }
            }
        }
    }
}

// ---------------- split-K reduce (32 bf16 slices) + LayerNorm over C=512, output bf16 ----------------
__global__ __launch_bounds__(256) void reduce_ln_bf16(
    const u16* __restrict__ part, u16* __restrict__ out,
    const float* __restrict__ gamma, const float* __restrict__ beta)
{
    int row = blockIdx.x, tid = threadIdx.x;
    const unsigned* base = (const unsigned*)(part + (size_t)row * 512) + tid;
    float2 v = {0.f, 0.f};
    #pragma unroll 8
    for (int z = 0; z < 32; ++z) {
        unsigned u = base[(size_t)z * 131072];   // 262144 u16 = 131072 dwords per slice
        v.x += __uint_as_float(u << 16);
        v.y += __uint_as_float(u & 0xffff0000u);
    }
    float s = v.x + v.y, ss = v.x * v.x + v.y * v.y;
    #pragma unroll
    for (int off = 32; off > 0; off >>= 1) {
        s  += __shfl_down(s, off);
        ss += __shfl_down(ss, off);
    }
    __shared__ float red[8];
    __shared__ float stats[2];
    int wvi = tid >> 6, lane = tid & 63;
    if (lane == 0) { red[wvi * 2] = s; red[wvi * 2 + 1] = ss; }
    __syncthreads();
    if (tid == 0) {
        float S = red[0] + red[2] + red[4] + red[6];
        float SS = red[1] + red[3] + red[5] + red[7];
        float mean = S * (1.f / 512.f);
        float var = SS * (1.f / 512.f) - mean * mean;
        stats[0] = mean; stats[1] = rsqrtf(var + 1e-3f);
    }
    __syncthreads();
    float mean = stats[0], rstd = stats[1];
    float o0 = (v.x - mean) * rstd * gamma[tid * 2]     + beta[tid * 2];
    float o1 = (v.y - mean) * rstd * gamma[tid * 2 + 1] + beta[tid * 2 + 1];
    unsigned w = (unsigned)f2bf(o0) | ((unsigned)f2bf(o1) << 16);
    *(unsigned*)&out[(size_t)row * 512 + tid * 2] = w;
}

// ---------------- MFMA attention: per block = 1 bh, 128 queries, 64 keys ----------------
// q_bf [bh][4096][64] bf16; kvf fp32: K at [bh][m][d], V^T at 262144 + [bh][d][m]
__global__ __launch_bounds__(256) void attn_mfma(
    const u16* __restrict__ qbf, const float* __restrict__ kvf, u16* __restrict__ attn_out)
{
    __shared__ u16 Ksh[64 * 64];      // [key][d]
    __shared__ u16 Vt[64 * 64];       // [d][key]
    __shared__ u16 Psh[4][32 * 64];   // per-wave P [qrow][key]
    const int bh = blockIdx.x, qt = blockIdx.y;
    const int tid = threadIdx.x;
    const int wv = tid >> 6, lane = tid & 63;
    const int quad = lane >> 4, l15 = lane & 15;

    {   // stage K (bf16) and V^T (bf16)
        const float* kb = kvf + (size_t)bh * 4096;
        const float* vb = kvf + 262144 + (size_t)bh * 4096;
        for (int t = tid; t < 2048; t += 256) {
            float2 a = ((const float2*)kb)[t];
            ((unsigned*)Ksh)[t] = (unsigned)f2bf(a.x) | ((unsigned)f2bf(a.y) << 16);
            float2 b2 = ((const float2*)vb)[t];
            ((unsigned*)Vt)[t] = (unsigned)f2bf(b2.x) | ((unsigned)f2bf(b2.y) << 16);
        }
    }
    __syncthreads();

    // Q fragments straight from global: rows q0+i*16+l15, d = ks*32+quad*8
    const u16* qb = qbf + ((size_t)bh * 4096 + qt * 128 + wv * 32) * 64;
    bf16x8 qf[2][2];
    #pragma unroll
    for (int i = 0; i < 2; ++i)
        #pragma unroll
        for (int ks = 0; ks < 2; ++ks)
            qf[i][ks] = *(const bf16x8*)(qb + (i * 16 + l15) * 64 + ks * 32 + quad * 8);

    // S = Q @ K^T  (contraction over d=64, two k-steps)
    floatx4 s[2][4];
    #pragma unroll
    for (int i = 0; i < 2; ++i)
        #pragma unroll
        for (int j = 0; j < 4; ++j)
            s[i][j] = (floatx4){0.f, 0.f, 0.f, 0.f};
    #pragma unroll
    for (int j = 0; j < 4; ++j) {
        #pragma unroll
        for (int ks = 0; ks < 2; ++ks) {
            bf16x8 kf = *(const bf16x8*)&Ksh[(j * 16 + l15) * 64 + ks * 32 + quad * 8];
            #pragma unroll
            for (int i = 0; i < 2; ++i)
                s[i][j] = __builtin_amdgcn_mfma_f32_16x16x32_bf16(qf[i][ks], kf, s[i][j], 0, 0, 0);
        }
    }

    // softmax (no max-shift: |s*scale| <~ 2): exp, write unnormalized P to LDS, row-sum
    u16* P = Psh[wv];
    float rs[2][4];
    #pragma unroll
    for (int i = 0; i < 2; ++i)
        #pragma unroll
        for (int r = 0; r < 4; ++r) rs[i][r] = 0.f;
    #pragma unroll
    for (int i = 0; i < 2; ++i)
        #pragma unroll
        for (int j = 0; j < 4; ++j)
            #pragma unroll
            for (int r = 0; r < 4; ++r) {
                float e = __expf(s[i][j][r] * 0.125f);
                rs[i][r] += e;
                P[(i * 16 + quad * 4 + r) * 64 + j * 16 + l15] = f2bf(e);
            }
    #pragma unroll
    for (int m = 1; m < 16; m <<= 1)
        #pragma unroll
        for (int i = 0; i < 2; ++i)
            #pragma unroll
            for (int r = 0; r < 4; ++r)
                rs[i][r] += __shfl_xor(rs[i][r], m);
    __syncthreads();   // P LDS write -> read ordering

    // O = P @ V  (contraction over keys=64, two k-steps); V^T rows are d-rows
    floatx4 o[2][4];
    #pragma unroll
    for (int i = 0; i < 2; ++i)
        #pragma unroll
        for (int j = 0; j < 4; ++j)
            o[i][j] = (floatx4){0.f, 0.f, 0.f, 0.f};
    #pragma unroll
    for (int ks = 0; ks < 2; ++ks) {
        bf16x8 pf[2];
        #pragma unroll
        for (int i = 0; i < 2; ++i)
            pf[i] = *(const bf16x8*)&P[(i * 16 + l15) * 64 + ks * 32 + quad * 8];
        #pragma unroll
        for (int j = 0; j < 4; ++j) {
            bf16x8 vf = *(const bf16x8*)&Vt[(j * 16 + l15) * 64 + ks * 32 + quad * 8];
            #pragma unroll
            for (int i = 0; i < 2; ++i)
                o[i][j] = __builtin_amdgcn_mfma_f32_16x16x32_bf16(pf[i], vf, o[i][j], 0, 0, 0);
        }
    }

    // normalize + store bf16 to [b][n][h*64+d]
    const int b = bh >> 3, h = bh & 7;
    #pragma unroll
    for (int i = 0; i < 2; ++i) {
        #pragma unroll
        for (int r = 0; r < 4; ++r) {
            float inv = 1.f / rs[i][r];
            int n = qt * 128 + wv * 32 + i * 16 + quad * 4 + r;
            u16* op = attn_out + ((size_t)(b * 4096 + n)) * 512 + h * 64;
            #pragma unroll
            for (int j = 0; j < 4; ++j)
                op[j * 16 + l15] = f2bf(o[i][j][r] * inv);
        }
    }
}

extern "C" void kernel_launch(void* const* d_in, const int* in_sizes, int n_in,
                              void* d_out, int out_size, void* d_ws, size_t ws_size,
                              hipStream_t stream) {
    const float* x      = (const float*)d_in[0];
    const float* Wq     = (const float*)d_in[1];
    const float* Wkv    = (const float*)d_in[2];
    const float* conv_w = (const float*)d_in[3];
    const float* gamma  = (const float*)d_in[4];
    const float* beta   = (const float*)d_in[5];
    const float* Wp     = (const float*)d_in[6];
    const float* bp     = (const float*)d_in[7];
    float* out = (float*)d_out;

    char* w = (char*)d_ws;
    const size_t MB = 1ull << 20;
    u16*   x_bf      = (u16*)(w + 0);           // 32 MB  [32768 x 512] bf16
    u16*   WconvT    = (u16*)(w + 32 * MB);     // 32 MB  [512 x 32768] bf16
    u16*   WqTp      = (u16*)(w + 64 * MB);     // 0.5 MB [512 x 512] (head-major cols)
    u16*   WkvT      = (u16*)(w + 65 * MB);     // 1 MB   [1024 x 512]
    u16*   WpT       = (u16*)(w + 66 * MB);     // 0.5 MB [512 x 512]
    u16*   q_bf      = (u16*)(w + 67 * MB);     // 32 MB  [64][4096][64] bf16
    u16*   fmap_part = (u16*)(w + 99 * MB);     // 16 MB  [32][512 x 512] bf16
    u16*   fmap_ln   = (u16*)(w + 131 * MB);    // 0.5 MB [512 x 512] bf16
    float* kv_f      = (float*)(w + 132 * MB);  // 2 MB   K + V^T fp32
    u16*   attn_bf   = (u16*)(w + 134 * MB);    // 32 MB  [32768 x 512] bf16

    cast_x_kernel<<<2048, 256, 0, stream>>>(x, x_bf);
    prep2_kernel<<<3072, 256, 0, stream>>>(conv_w, WconvT, Wq, WqTp, Wp, WpT, Wkv, WkvT);

    // q = x @ Wq -> bf16 permuted [bh][n][d] (coalesced via pre-permuted B cols)
    gemm_bt<1, 0><<<dim3(4, 256, 1), 256, 0, stream>>>(x_bf, WqTp, (float*)q_bf, 32768, 512, 512, 512, nullptr);
    // conv as implicit patch GEMM, split-K 32 -> bf16 partials
    gemm_bt<0, 1><<<dim3(4, 4, 32), 256, 0, stream>>>(x_bf, WconvT, (float*)fmap_part, 512, 512, 32768, 1024, nullptr);
    reduce_ln_bf16<<<512, 256, 0, stream>>>(fmap_part, fmap_ln, gamma, beta);
    // kv = ln(fmap) @ Wkv -> K and V^T (plain stores, no split-K)
    gemm_bt<2, 0><<<dim3(8, 4, 1), 256, 0, stream>>>(fmap_ln, WkvT, kv_f, 512, 1024, 512, 512, nullptr);
    attn_mfma<<<dim3(64, 32), 256, 0, stream>>>(q_bf, kv_f, attn_bf);
    // final projection + bias
    gemm_bt<3, 0><<<dim3(4, 256, 1), 256, 0, stream>>>(attn_bf, WpT, out, 32768, 512, 512, 512, bp);
}

// Round 5
// 317.407 us; speedup vs baseline: 1.0040x; 1.0040x over previous
//
#include <hip/hip_runtime.h>

typedef unsigned short u16;
typedef __bf16 bf16x8 __attribute__((ext_vector_type(8)));
typedef float floatx4 __attribute__((ext_vector_type(4)));

__device__ __forceinline__ u16 f2bf(float f) {
    unsigned u = __float_as_uint(f);
    u += 0x7fff + ((u >> 16) & 1);   // round-to-nearest-even
    return (u16)(u >> 16);
}

#define GLOAD_LDS16(g, l) __builtin_amdgcn_global_load_lds( \
    (const __attribute__((address_space(1))) void*)(g),      \
    (__attribute__((address_space(3))) void*)(l), 16, 0, 0)

// WconvT row stride: 32768 + 64 u16 = 65664 B = 513 cache lines -> breaks L2 set aliasing
#define WCONV_STRIDE 32832

// ---------------- cast x fp32 -> bf16, copy-ubench shape: 2x float4 in, 1x uint4 out ----------------
__global__ __launch_bounds__(256) void cast_x_kernel(
    const float* __restrict__ x, u16* __restrict__ x_bf)
{
    const int tid = threadIdx.x;
    const size_t base = (size_t)blockIdx.x * 1024 + tid;   // uint4 units
    const float4* src = (const float4*)x;
    uint4* dst = (uint4*)x_bf;
    float4 a[4], b[4];
    #pragma unroll
    for (int i = 0; i < 4; ++i) {
        a[i] = src[(base + i * 256) * 2];
        b[i] = src[(base + i * 256) * 2 + 1];
    }
    #pragma unroll
    for (int i = 0; i < 4; ++i) {
        uint4 o;
        o.x = (unsigned)f2bf(a[i].x) | ((unsigned)f2bf(a[i].y) << 16);
        o.y = (unsigned)f2bf(a[i].z) | ((unsigned)f2bf(a[i].w) << 16);
        o.z = (unsigned)f2bf(b[i].x) | ((unsigned)f2bf(b[i].y) << 16);
        o.w = (unsigned)f2bf(b[i].z) | ((unsigned)f2bf(b[i].w) << 16);
        dst[base + i * 256] = o;
    }
}

// ---------------- transposes: conv_w (blocks 0..2047) + small weights (2048..3071) ----------------
__global__ __launch_bounds__(256) void prep2_kernel(
    const float* __restrict__ conv_w, u16* __restrict__ WconvT,
    const float* __restrict__ Wq, u16* __restrict__ WqTp,
    const float* __restrict__ Wp, u16* __restrict__ WpT,
    const float* __restrict__ Wkv, u16* __restrict__ WkvT)
{
    int blk = blockIdx.x;
    const int tid = threadIdx.x;
    __shared__ __align__(16) char smem[16896];

    if (blk < 2048) {
        // conv_w [32768 k][512 cout] fp32 -> WconvT [512 cout][32768 k] bf16 (padded row stride)
        // tile: 64 couts x 128 k. LDS staged bf16 [128 k][66 cout] (pitch 66 u16).
        u16 (*T)[66] = (u16(*)[66])smem;
        const int by = blk >> 8;        // 0..7   cout chunk
        const int bx = blk & 255;       // 0..255 k chunk
        const int c0 = by * 64, k0 = bx * 128;
        const int f = tid & 15, kl = tid >> 4;
        #pragma unroll
        for (int it = 0; it < 8; ++it) {
            int k = kl + it * 16;
            float4 v = *(const float4*)(conv_w + (size_t)(k0 + k) * 512 + c0 + f * 4);
            *(unsigned*)&T[k][f * 4]     = (unsigned)f2bf(v.x) | ((unsigned)f2bf(v.y) << 16);
            *(unsigned*)&T[k][f * 4 + 2] = (unsigned)f2bf(v.z) | ((unsigned)f2bf(v.w) << 16);
        }
        __syncthreads();
        const int cl = tid >> 6, p = tid & 63;
        #pragma unroll
        for (int it = 0; it < 16; ++it) {
            int c = cl + it * 4;
            unsigned lo = T[p * 2][c], hi = T[p * 2 + 1][c];
            // one full 256 B contiguous row segment per wave
            *(unsigned*)&WconvT[(size_t)(c0 + c) * WCONV_STRIDE + k0 + p * 2] = lo | (hi << 16);
        }
        return;
    }
    blk -= 2048;

    const float* in; u16* outp; int R, Cn, bx, by; bool perm = false;
    if (blk < 256)      { in = Wq;  outp = WqTp; R = 512; Cn = 512;  bx = blk & 15; by = blk >> 4; perm = true; }
    else if (blk < 512) { blk -= 256; in = Wp;  outp = WpT;  R = 512; Cn = 512;  bx = blk & 15; by = blk >> 4; }
    else                { blk -= 512; in = Wkv; outp = WkvT; R = 512; Cn = 1024; bx = blk & 31; by = blk >> 5; }
    float (*tile)[33] = (float(*)[33])smem;
    const int c0 = bx * 32, r0 = by * 32;
    const int tx = tid & 31, ty = tid >> 5;
    #pragma unroll
    for (int yy = 0; yy < 4; ++yy)
        tile[ty + yy * 8][tx] = in[(size_t)(r0 + ty + yy * 8) * Cn + c0 + tx];
    __syncthreads();
    #pragma unroll
    for (int yy = 0; yy < 4; ++yy) {
        int cc = c0 + ty + yy * 8;
        int np = perm ? ((cc & 7) * 64 + (cc >> 3)) : cc;
        outp[(size_t)np * R + r0 + tx] = f2bf(tile[tx][ty + yy * 8]);
    }
}

// ---------------- MFMA GEMM: C[M,N] = A[M,K] * B^T[N,K]  (bf16 in, fp32 acc) ----------------
// BK=64 staged as two [128][32] sub-tiles per operand (keeps 64B LDS row stride).
// BS = B row stride in elements (>= K; lets WconvT carry L2-set-dealiasing padding).
// ASRC 0: A is plain [M,K] bf16.  ASRC 1: A rows are conv patches gathered from x_bf.
// MODE 0: split-K partial store bf16  ((u16*)out)[z*262144 + m*512 + n]   (conv fmap)
// MODE 1: q store (B cols pre-permuted head-major): h=n>>6, d=n&63 -> q_bf[(b*8+h)*4096+nn][d]
// MODE 2: kv permute (plain store)  K: kv[(b*8+h)*64+m][d]; V transposed: kv[V + (b*8+h)*64+d][m]
// MODE 3: out + bias  -> d_out[M,512] fp32
// MODE != 0: XCD-chunked block swizzle (blocks sharing an A panel land on one XCD's L2)
template<int MODE, int ASRC>
__global__ __launch_bounds__(256) void gemm_bt(
    const u16* __restrict__ A, const u16* __restrict__ B, float* __restrict__ out,
    int M, int N, int K, int BS, int KC, const float* __restrict__ bias)
{
    __shared__ u16 As[2][128 * 32];
    __shared__ u16 Bs[2][128 * 32];
    const int tid = threadIdx.x;
    const int wv = tid >> 6, lane = tid & 63;
    const int quad = lane >> 4, l15 = lane & 15;

    constexpr int GX = (MODE == 2) ? 8 : 4;
    int id = blockIdx.y * GX + blockIdx.x;
    if (MODE != 0) {
        const int nwg = GX * gridDim.y;          // divisible by 8 for all uses
        id = (id & 7) * (nwg >> 3) + (id >> 3);  // bijective chunked XCD swizzle
    }
    const int bm = (id / GX) * 128, bn = (id % GX) * 128;
    const int k0 = blockIdx.z * KC;
    const int wr = wv >> 1, wc = wv & 1;

    floatx4 acc[4][4];
    #pragma unroll
    for (int i = 0; i < 4; ++i)
        #pragma unroll
        for (int j = 0; j < 4; ++j)
            acc[i][j] = (floatx4){0.f, 0.f, 0.f, 0.f};

    for (int kt = 0; kt < KC; kt += 64) {
        const int kk = k0 + kt;
        #pragma unroll
        for (int hf = 0; hf < 2; ++hf) {
            #pragma unroll
            for (int c2 = 0; c2 < 2; ++c2) {
                int idx = ((wv * 2 + c2) * 64 + lane) * 8;   // element offset in [128][32] half
                int row = idx >> 5, col = idx & 31;
                int k = kk + hf * 32 + col;
                if (ASRC == 0) {
                    const u16* ga = A + (size_t)(bm + row) * K + k;
                    GLOAD_LDS16(ga, &As[hf][(wv * 2 + c2) * 512]);
                } else {
                    // conv patch gather: row p=(b,ii,jj), k=(r1,r2,cin)
                    int p = bm + row;
                    int b = p >> 6, ij = p & 63, ii = ij >> 3, jj = ij & 7;
                    int r12 = k >> 9, r1 = r12 >> 3, r2 = r12 & 7;
                    int n = (ii * 8 + r1) * 64 + jj * 8 + r2;
                    const u16* ga = A + ((size_t)(b * 4096 + n)) * 512 + (k & 511);
                    GLOAD_LDS16(ga, &As[hf][(wv * 2 + c2) * 512]);
                }
                const u16* gb = B + (size_t)(bn + row) * BS + k;
                GLOAD_LDS16(gb, &Bs[hf][(wv * 2 + c2) * 512]);
            }
        }
        __syncthreads();
        #pragma unroll
        for (int ks = 0; ks < 2; ++ks) {
            bf16x8 af[4], bfr[4];
            #pragma unroll
            for (int i = 0; i < 4; ++i)
                af[i] = *(const bf16x8*)&As[ks][(wr * 64 + i * 16 + l15) * 32 + quad * 8];
            #pragma unroll
            for (int j = 0; j < 4; ++j)
                bfr[j] = *(const bf16x8*)&Bs[ks][(wc * 64 + j * 16 + l15) * 32 + quad * 8];
            #pragma unroll
            for (int i = 0; i < 4; ++i)
                #pragma unroll
                for (int j = 0; j < 4; ++j)
                    acc[i][j] = __builtin_amdgcn_mfma_f32_16x16x32_bf16(af[i], bfr[j], acc[i][j], 0, 0, 0);
        }
        __syncthreads();
    }

    #pragma unroll
    for (int i = 0; i < 4; ++i) {
        #pragma unroll
        for (int j = 0; j < 4; ++j) {
            #pragma unroll
            for (int r = 0; r < 4; ++r) {
                int m = bm + wr * 64 + i * 16 + quad * 4 + r;
                int n = bn + wc * 64 + j * 16 + l15;
                float v = acc[i][j][r];
                if (MODE == 0) {
                    ((u16*)out)[(size_t)blockIdx.z * 262144 + (size_t)m * N + n] = f2bf(v);
                } else if (MODE == 1) {
                    int b = m >> 12, nn = m & 4095;
                    int h = n >> 6, d = n & 63;     // B columns pre-permuted head-major
                    ((u16*)out)[((size_t)((b * 8 + h) * 4096 + nn)) * 64 + d] = f2bf(v);
                } else if (MODE == 2) {
                    int b = m >> 6, mm = m & 63;
                    int f = n >> 9, c = n & 511, h = c >> 6, d = c & 63;
                    size_t idx;
                    if (f == 0) idx = ((size_t)((b * 8 + h) * 64 + mm)) * 64 + d;
                    else        idx = 262144 + ((size_t)((b * 8 + h) * 64 + d)) * 64 + mm;  // V^T
                    out[idx] = v;
                } else {
                    out[(size_t)m * 512 + n] = v + bias[n];
                }
            }
        }
    }
}

// ---------------- split-K reduce (32 bf16 slices) + LayerNorm over C=512, output bf16 ----------------
__global__ __launch_bounds__(256) void reduce_ln_bf16(
    const u16* __restrict__ part, u16* __restrict__ out,
    const float* __restrict__ gamma, const float* __restrict__ beta)
{
    int row = blockIdx.x, tid = threadIdx.x;
    const unsigned* base = (const unsigned*)(part + (size_t)row * 512) + tid;
    float2 v = {0.f, 0.f};
    #pragma unroll 8
    for (int z = 0; z < 32; ++z) {
        unsigned u = base[(size_t)z * 131072];   // 262144 u16 = 131072 dwords per slice
        v.x += __uint_as_float(u << 16);
        v.y += __uint_as_float(u & 0xffff0000u);
    }
    float s = v.x + v.y, ss = v.x * v.x + v.y * v.y;
    #pragma unroll
    for (int off = 32; off > 0; off >>= 1) {
        s  += __shfl_down(s, off);
        ss += __shfl_down(ss, off);
    }
    __shared__ float red[8];
    __shared__ float stats[2];
    int wvi = tid >> 6, lane = tid & 63;
    if (lane == 0) { red[wvi * 2] = s; red[wvi * 2 + 1] = ss; }
    __syncthreads();
    if (tid == 0) {
        float S = red[0] + red[2] + red[4] + red[6];
        float SS = red[1] + red[3] + red[5] + red[7];
        float mean = S * (1.f / 512.f);
        float var = SS * (1.f / 512.f) - mean * mean;
        stats[0] = mean; stats[1] = rsqrtf(var + 1e-3f);
    }
    __syncthreads();
    float mean = stats[0], rstd = stats[1];
    float o0 = (v.x - mean) * rstd * gamma[tid * 2]     + beta[tid * 2];
    float o1 = (v.y - mean) * rstd * gamma[tid * 2 + 1] + beta[tid * 2 + 1];
    unsigned w = (unsigned)f2bf(o0) | ((unsigned)f2bf(o1) << 16);
    *(unsigned*)&out[(size_t)row * 512 + tid * 2] = w;
}

// ---------------- MFMA attention: per block = 1 bh, 128 queries, 64 keys ----------------
// q_bf [bh][4096][64] bf16; kvf fp32: K at [bh][m][d], V^T at 262144 + [bh][d][m]
__global__ __launch_bounds__(256) void attn_mfma(
    const u16* __restrict__ qbf, const float* __restrict__ kvf, u16* __restrict__ attn_out)
{
    __shared__ u16 Ksh[64 * 64];      // [key][d]
    __shared__ u16 Vt[64 * 64];       // [d][key]
    __shared__ u16 Psh[4][32 * 64];   // per-wave P [qrow][key]
    const int bh = blockIdx.x, qt = blockIdx.y;
    const int tid = threadIdx.x;
    const int wv = tid >> 6, lane = tid & 63;
    const int quad = lane >> 4, l15 = lane & 15;

    {   // stage K (bf16) and V^T (bf16)
        const float* kb = kvf + (size_t)bh * 4096;
        const float* vb = kvf + 262144 + (size_t)bh * 4096;
        for (int t = tid; t < 2048; t += 256) {
            float2 a = ((const float2*)kb)[t];
            ((unsigned*)Ksh)[t] = (unsigned)f2bf(a.x) | ((unsigned)f2bf(a.y) << 16);
            float2 b2 = ((const float2*)vb)[t];
            ((unsigned*)Vt)[t] = (unsigned)f2bf(b2.x) | ((unsigned)f2bf(b2.y) << 16);
        }
    }
    __syncthreads();

    // Q fragments straight from global: rows q0+i*16+l15, d = ks*32+quad*8
    const u16* qb = qbf + ((size_t)bh * 4096 + qt * 128 + wv * 32) * 64;
    bf16x8 qf[2][2];
    #pragma unroll
    for (int i = 0; i < 2; ++i)
        #pragma unroll
        for (int ks = 0; ks < 2; ++ks)
            qf[i][ks] = *(const bf16x8*)(qb + (i * 16 + l15) * 64 + ks * 32 + quad * 8);

    // S = Q @ K^T  (contraction over d=64, two k-steps)
    floatx4 s[2][4];
    #pragma unroll
    for (int i = 0; i < 2; ++i)
        #pragma unroll
        for (int j = 0; j < 4; ++j)
            s[i][j] = (floatx4){0.f, 0.f, 0.f, 0.f};
    #pragma unroll
    for (int j = 0; j < 4; ++j) {
        #pragma unroll
        for (int ks = 0; ks < 2; ++ks) {
            bf16x8 kf = *(const bf16x8*)&Ksh[(j * 16 + l15) * 64 + ks * 32 + quad * 8];
            #pragma unroll
            for (int i = 0; i < 2; ++i)
                s[i][j] = __builtin_amdgcn_mfma_f32_16x16x32_bf16(qf[i][ks], kf, s[i][j], 0, 0, 0);
        }
    }

    // softmax (no max-shift: |s*scale| <~ 2): exp, write unnormalized P to LDS, row-sum
    u16* P = Psh[wv];
    float rs[2][4];
    #pragma unroll
    for (int i = 0; i < 2; ++i)
        #pragma unroll
        for (int r = 0; r < 4; ++r) rs[i][r] = 0.f;
    #pragma unroll
    for (int i = 0; i < 2; ++i)
        #pragma unroll
        for (int j = 0; j < 4; ++j)
            #pragma unroll
            for (int r = 0; r < 4; ++r) {
                float e = __expf(s[i][j][r] * 0.125f);
                rs[i][r] += e;
                P[(i * 16 + quad * 4 + r) * 64 + j * 16 + l15] = f2bf(e);
            }
    #pragma unroll
    for (int m = 1; m < 16; m <<= 1)
        #pragma unroll
        for (int i = 0; i < 2; ++i)
            #pragma unroll
            for (int r = 0; r < 4; ++r)
                rs[i][r] += __shfl_xor(rs[i][r], m);
    __syncthreads();   // P LDS write -> read ordering

    // O = P @ V  (contraction over keys=64, two k-steps); V^T rows are d-rows
    floatx4 o[2][4];
    #pragma unroll
    for (int i = 0; i < 2; ++i)
        #pragma unroll
        for (int j = 0; j < 4; ++j)
            o[i][j] = (floatx4){0.f, 0.f, 0.f, 0.f};
    #pragma unroll
    for (int ks = 0; ks < 2; ++ks) {
        bf16x8 pf[2];
        #pragma unroll
        for (int i = 0; i < 2; ++i)
            pf[i] = *(const bf16x8*)&P[(i * 16 + l15) * 64 + ks * 32 + quad * 8];
        #pragma unroll
        for (int j = 0; j < 4; ++j) {
            bf16x8 vf = *(const bf16x8*)&Vt[(j * 16 + l15) * 64 + ks * 32 + quad * 8];
            #pragma unroll
            for (int i = 0; i < 2; ++i)
                o[i][j] = __builtin_amdgcn_mfma_f32_16x16x32_bf16(pf[i], vf, o[i][j], 0, 0, 0);
        }
    }

    // normalize + store bf16 to [b][n][h*64+d]
    const int b = bh >> 3, h = bh & 7;
    #pragma unroll
    for (int i = 0; i < 2; ++i) {
        #pragma unroll
        for (int r = 0; r < 4; ++r) {
            float inv = 1.f / rs[i][r];
            int n = qt * 128 + wv * 32 + i * 16 + quad * 4 + r;
            u16* op = attn_out + ((size_t)(b * 4096 + n)) * 512 + h * 64;
            #pragma unroll
            for (int j = 0; j < 4; ++j)
                op[j * 16 + l15] = f2bf(o[i][j][r] * inv);
        }
    }
}

extern "C" void kernel_launch(void* const* d_in, const int* in_sizes, int n_in,
                              void* d_out, int out_size, void* d_ws, size_t ws_size,
                              hipStream_t stream) {
    const float* x      = (const float*)d_in[0];
    const float* Wq     = (const float*)d_in[1];
    const float* Wkv    = (const float*)d_in[2];
    const float* conv_w = (const float*)d_in[3];
    const float* gamma  = (const float*)d_in[4];
    const float* beta   = (const float*)d_in[5];
    const float* Wp     = (const float*)d_in[6];
    const float* bp     = (const float*)d_in[7];
    float* out = (float*)d_out;

    char* w = (char*)d_ws;
    const size_t MB = 1ull << 20;
    u16*   x_bf      = (u16*)(w + 0);           // 32 MB  [32768 x 512] bf16
    u16*   WconvT    = (u16*)(w + 32 * MB);     // 34 MB  [512 x 32832] bf16 (padded stride)
    u16*   WqTp      = (u16*)(w + 66 * MB);     // 0.5 MB [512 x 512] (head-major cols)
    u16*   WkvT      = (u16*)(w + 67 * MB);     // 1 MB   [1024 x 512]
    u16*   WpT       = (u16*)(w + 68 * MB);     // 0.5 MB [512 x 512]
    u16*   q_bf      = (u16*)(w + 69 * MB);     // 32 MB  [64][4096][64] bf16
    u16*   fmap_part = (u16*)(w + 101 * MB);    // 16 MB  [32][512 x 512] bf16
    u16*   fmap_ln   = (u16*)(w + 117 * MB);    // 0.5 MB [512 x 512] bf16
    float* kv_f      = (float*)(w + 118 * MB);  // 2 MB   K + V^T fp32
    u16*   attn_bf   = (u16*)(w + 120 * MB);    // 32 MB  [32768 x 512] bf16

    cast_x_kernel<<<2048, 256, 0, stream>>>(x, x_bf);
    prep2_kernel<<<3072, 256, 0, stream>>>(conv_w, WconvT, Wq, WqTp, Wp, WpT, Wkv, WkvT);

    // q = x @ Wq -> bf16 permuted [bh][n][d] (coalesced via pre-permuted B cols)
    gemm_bt<1, 0><<<dim3(4, 256, 1), 256, 0, stream>>>(x_bf, WqTp, (float*)q_bf, 32768, 512, 512, 512, 512, nullptr);
    // conv as implicit patch GEMM, split-K 32 -> bf16 partials (B rows padded to 32832)
    gemm_bt<0, 1><<<dim3(4, 4, 32), 256, 0, stream>>>(x_bf, WconvT, (float*)fmap_part, 512, 512, 32768, WCONV_STRIDE, 1024, nullptr);
    reduce_ln_bf16<<<512, 256, 0, stream>>>(fmap_part, fmap_ln, gamma, beta);
    // kv = ln(fmap) @ Wkv -> K and V^T (plain stores, no split-K)
    gemm_bt<2, 0><<<dim3(8, 4, 1), 256, 0, stream>>>(fmap_ln, WkvT, kv_f, 512, 1024, 512, 512, 512, nullptr);
    attn_mfma<<<dim3(64, 32), 256, 0, stream>>>(q_bf, kv_f, attn_bf);
    // final projection + bias
    gemm_bt<3, 0><<<dim3(4, 256, 1), 256, 0, stream>>>(attn_bf, WpT, out, 32768, 512, 512, 512, 512, bp);
}

// Round 6
// 314.040 us; speedup vs baseline: 1.0148x; 1.0107x over previous
//
#include <hip/hip_runtime.h>

typedef unsigned short u16;
typedef __bf16 bf16x8 __attribute__((ext_vector_type(8)));
typedef float floatx4 __attribute__((ext_vector_type(4)));

__device__ __forceinline__ u16 f2bf(float f) {
    unsigned u = __float_as_uint(f);
    u += 0x7fff + ((u >> 16) & 1);   // round-to-nearest-even
    return (u16)(u >> 16);
}

#define GLOAD_LDS16(g, l) __builtin_amdgcn_global_load_lds( \
    (const __attribute__((address_space(1))) void*)(g),      \
    (__attribute__((address_space(3))) void*)(l), 16, 0, 0)

// WconvT row stride: 32768 + 64 u16 = 65664 B = 513 cache lines -> breaks L2 set aliasing
#define WCONV_STRIDE 32832

// ---------------- prep: cast x + all weight transposes, one launch ----------------
// blocks [0,2048): cast x fp32->bf16 (2x float4 in, 1x uint4 out)
// blocks [2048,4096): conv_w transpose via 64x128 tiles (256 B read AND write segments)
// blocks [4096,5120): Wq (head-major perm) / Wp / Wkv transposes
__global__ __launch_bounds__(256) void prep_kernel(
    const float* __restrict__ x, u16* __restrict__ x_bf,
    const float* __restrict__ conv_w, u16* __restrict__ WconvT,
    const float* __restrict__ Wq, u16* __restrict__ WqTp,
    const float* __restrict__ Wp, u16* __restrict__ WpT,
    const float* __restrict__ Wkv, u16* __restrict__ WkvT)
{
    int blk = blockIdx.x;
    const int tid = threadIdx.x;

    if (blk < 2048) {
        const size_t base = (size_t)blk * 1024 + tid;   // uint4 units
        const float4* src = (const float4*)x;
        uint4* dst = (uint4*)x_bf;
        float4 a[4], b[4];
        #pragma unroll
        for (int i = 0; i < 4; ++i) {
            a[i] = src[(base + i * 256) * 2];
            b[i] = src[(base + i * 256) * 2 + 1];
        }
        #pragma unroll
        for (int i = 0; i < 4; ++i) {
            uint4 o;
            o.x = (unsigned)f2bf(a[i].x) | ((unsigned)f2bf(a[i].y) << 16);
            o.y = (unsigned)f2bf(a[i].z) | ((unsigned)f2bf(a[i].w) << 16);
            o.z = (unsigned)f2bf(b[i].x) | ((unsigned)f2bf(b[i].y) << 16);
            o.w = (unsigned)f2bf(b[i].z) | ((unsigned)f2bf(b[i].w) << 16);
            dst[base + i * 256] = o;
        }
        return;
    }
    blk -= 2048;

    __shared__ __align__(16) char smem[16896];

    if (blk < 2048) {
        // conv_w [32768 k][512 cout] fp32 -> WconvT [512 cout][32768 k] bf16 (padded row stride)
        u16 (*T)[66] = (u16(*)[66])smem;
        const int by = blk >> 8;        // 0..7   cout chunk
        const int bx = blk & 255;       // 0..255 k chunk
        const int c0 = by * 64, k0 = bx * 128;
        const int f = tid & 15, kl = tid >> 4;
        #pragma unroll
        for (int it = 0; it < 8; ++it) {
            int k = kl + it * 16;
            float4 v = *(const float4*)(conv_w + (size_t)(k0 + k) * 512 + c0 + f * 4);
            *(unsigned*)&T[k][f * 4]     = (unsigned)f2bf(v.x) | ((unsigned)f2bf(v.y) << 16);
            *(unsigned*)&T[k][f * 4 + 2] = (unsigned)f2bf(v.z) | ((unsigned)f2bf(v.w) << 16);
        }
        __syncthreads();
        const int cl = tid >> 6, p = tid & 63;
        #pragma unroll
        for (int it = 0; it < 16; ++it) {
            int c = cl + it * 4;
            unsigned lo = T[p * 2][c], hi = T[p * 2 + 1][c];
            *(unsigned*)&WconvT[(size_t)(c0 + c) * WCONV_STRIDE + k0 + p * 2] = lo | (hi << 16);
        }
        return;
    }
    blk -= 2048;

    const float* in; u16* outp; int R, Cn, bx, by; bool perm = false;
    if (blk < 256)      { in = Wq;  outp = WqTp; R = 512; Cn = 512;  bx = blk & 15; by = blk >> 4; perm = true; }
    else if (blk < 512) { blk -= 256; in = Wp;  outp = WpT;  R = 512; Cn = 512;  bx = blk & 15; by = blk >> 4; }
    else                { blk -= 512; in = Wkv; outp = WkvT; R = 512; Cn = 1024; bx = blk & 31; by = blk >> 5; }
    float (*tile)[33] = (float(*)[33])smem;
    const int c0 = bx * 32, r0 = by * 32;
    const int tx = tid & 31, ty = tid >> 5;
    #pragma unroll
    for (int yy = 0; yy < 4; ++yy)
        tile[ty + yy * 8][tx] = in[(size_t)(r0 + ty + yy * 8) * Cn + c0 + tx];
    __syncthreads();
    #pragma unroll
    for (int yy = 0; yy < 4; ++yy) {
        int cc = c0 + ty + yy * 8;
        int np = perm ? ((cc & 7) * 64 + (cc >> 3)) : cc;
        outp[(size_t)np * R + r0 + tx] = f2bf(tile[tx][ty + yy * 8]);
    }
}

// ---------------- MFMA GEMM body: C[M,N] = A[M,K] * B^T[N,K]  (bf16 in, fp32 acc) ----------------
// Min-2-phase pipeline: BK=32 double-buffered LDS (2 x [128][32] per operand, 32 KB total),
// STAGE(t+1) issued BEFORE compute(t); ONE barrier per step (HBM latency hides under MFMAs).
// BS = B row stride (>= K; carries WconvT's L2-set-dealiasing padding).
// ASRC 0: A plain [M,K].  ASRC 1: A rows are conv patches gathered from x_bf.
// MODE 0: split-K partial bf16 store   MODE 1: q permuted store
// MODE 2: kv permute (K + V^T)         MODE 3: out + bias fp32
template<int MODE, int ASRC>
__device__ __forceinline__ void gemm_body(
    const u16* __restrict__ A, const u16* __restrict__ B, float* __restrict__ out,
    int M, int N, int K, int BS, int KC, const float* __restrict__ bias,
    int id, int zz, u16 (*As)[4096], u16 (*Bs)[4096])
{
    const int tid = threadIdx.x;
    const int wv = tid >> 6, lane = tid & 63;
    const int quad = lane >> 4, l15 = lane & 15;
    constexpr int GX = (MODE == 2) ? 8 : 4;
    const int bm = (id / GX) * 128, bn = (id % GX) * 128;
    const int k0 = zz * KC;
    const int wr = wv >> 1, wc = wv & 1;

    floatx4 acc[4][4];
    #pragma unroll
    for (int i = 0; i < 4; ++i)
        #pragma unroll
        for (int j = 0; j < 4; ++j)
            acc[i][j] = (floatx4){0.f, 0.f, 0.f, 0.f};

    auto stage = [&](int step, int buf) {
        const int kk = k0 + (step << 5);
        #pragma unroll
        for (int c2 = 0; c2 < 2; ++c2) {
            const int chunk = wv * 2 + c2;
            const int idx = (chunk * 64 + lane) * 8;   // element offset in [128][32]
            const int row = idx >> 5, col = idx & 31;
            const int k = kk + col;
            if (ASRC == 0) {
                GLOAD_LDS16(A + (size_t)(bm + row) * K + k, &As[buf][chunk * 512]);
            } else {
                int p = bm + row;
                int b = p >> 6, ij = p & 63, ii = ij >> 3, jj = ij & 7;
                int r12 = k >> 9, r1 = r12 >> 3, r2 = r12 & 7;
                int n = (ii * 8 + r1) * 64 + jj * 8 + r2;
                GLOAD_LDS16(A + ((size_t)(b * 4096 + n)) * 512 + (k & 511), &As[buf][chunk * 512]);
            }
            GLOAD_LDS16(B + (size_t)(bn + row) * BS + k, &Bs[buf][chunk * 512]);
        }
    };
    auto compute = [&](int buf) {
        bf16x8 af[4], bfr[4];
        #pragma unroll
        for (int i = 0; i < 4; ++i)
            af[i] = *(const bf16x8*)&As[buf][(wr * 64 + i * 16 + l15) * 32 + quad * 8];
        #pragma unroll
        for (int j = 0; j < 4; ++j)
            bfr[j] = *(const bf16x8*)&Bs[buf][(wc * 64 + j * 16 + l15) * 32 + quad * 8];
        #pragma unroll
        for (int i = 0; i < 4; ++i)
            #pragma unroll
            for (int j = 0; j < 4; ++j)
                acc[i][j] = __builtin_amdgcn_mfma_f32_16x16x32_bf16(af[i], bfr[j], acc[i][j], 0, 0, 0);
    };

    const int nsteps = KC >> 5;          // always even (KC multiple of 64)
    stage(0, 0);
    __syncthreads();
    for (int step = 0; step < nsteps; step += 2) {
        stage(step + 1, 1);              // step+1 <= nsteps-1 always
        compute(0);
        __syncthreads();                 // drains stage writes + compute(0) reads
        if (step + 2 < nsteps) stage(step + 2, 0);
        compute(1);
        __syncthreads();
    }

    #pragma unroll
    for (int i = 0; i < 4; ++i) {
        #pragma unroll
        for (int j = 0; j < 4; ++j) {
            #pragma unroll
            for (int r = 0; r < 4; ++r) {
                int m = bm + wr * 64 + i * 16 + quad * 4 + r;
                int n = bn + wc * 64 + j * 16 + l15;
                float v = acc[i][j][r];
                if (MODE == 0) {
                    ((u16*)out)[(size_t)zz * 262144 + (size_t)m * N + n] = f2bf(v);
                } else if (MODE == 1) {
                    int b = m >> 12, nn = m & 4095;
                    int h = n >> 6, d = n & 63;     // B columns pre-permuted head-major
                    ((u16*)out)[((size_t)((b * 8 + h) * 4096 + nn)) * 64 + d] = f2bf(v);
                } else if (MODE == 2) {
                    int b = m >> 6, mm = m & 63;
                    int f = n >> 9, c = n & 511, h = c >> 6, d = c & 63;
                    size_t idx;
                    if (f == 0) idx = ((size_t)((b * 8 + h) * 64 + mm)) * 64 + d;
                    else        idx = 262144 + ((size_t)((b * 8 + h) * 64 + d)) * 64 + mm;  // V^T
                    out[idx] = v;
                } else {
                    out[(size_t)m * 512 + n] = v + bias[n];
                }
            }
        }
    }
}

// thin wrapper: 1-D flat grid, XCD-chunked swizzle for non-split-K modes
template<int MODE, int ASRC>
__global__ __launch_bounds__(256) void gemm_bt(
    const u16* __restrict__ A, const u16* __restrict__ B, float* __restrict__ out,
    int M, int N, int K, int BS, int KC, const float* __restrict__ bias)
{
    __shared__ u16 As[2][4096], Bs[2][4096];
    int id = blockIdx.x;
    if (MODE != 0) {
        const int nwg = gridDim.x;       // divisible by 8 for all uses
        id = (id & 7) * (nwg >> 3) + (id >> 3);
    }
    gemm_body<MODE, ASRC>(A, B, out, M, N, K, BS, KC, bias, id, blockIdx.z, As, Bs);
}

// merged q-GEMM + conv-GEMM: conv (critical path) blocks first, q blocks fill behind
__global__ __launch_bounds__(256) void gemm_qconv(
    const u16* __restrict__ x_bf, const u16* __restrict__ WconvT, u16* __restrict__ fmap_part,
    const u16* __restrict__ WqTp, u16* __restrict__ q_bf)
{
    __shared__ u16 As[2][4096], Bs[2][4096];
    const int blk = blockIdx.x;
    if (blk < 512) {
        gemm_body<0, 1>(x_bf, WconvT, (float*)fmap_part, 512, 512, 32768, WCONV_STRIDE, 1024,
                        nullptr, blk & 15, blk >> 4, As, Bs);
    } else {
        int id = blk - 512;                      // 0..1023
        id = (id & 7) * 128 + (id >> 3);         // XCD-chunked swizzle, nwg=1024
        gemm_body<1, 0>(x_bf, WqTp, (float*)q_bf, 32768, 512, 512, 512, 512,
                        nullptr, id, 0, As, Bs);
    }
}

// ---------------- split-K reduce (32 bf16 slices) + LayerNorm over C=512, output bf16 ----------------
__global__ __launch_bounds__(256) void reduce_ln_bf16(
    const u16* __restrict__ part, u16* __restrict__ out,
    const float* __restrict__ gamma, const float* __restrict__ beta)
{
    int row = blockIdx.x, tid = threadIdx.x;
    const unsigned* base = (const unsigned*)(part + (size_t)row * 512) + tid;
    float2 v = {0.f, 0.f};
    #pragma unroll 8
    for (int z = 0; z < 32; ++z) {
        unsigned u = base[(size_t)z * 131072];   // 262144 u16 = 131072 dwords per slice
        v.x += __uint_as_float(u << 16);
        v.y += __uint_as_float(u & 0xffff0000u);
    }
    float s = v.x + v.y, ss = v.x * v.x + v.y * v.y;
    #pragma unroll
    for (int off = 32; off > 0; off >>= 1) {
        s  += __shfl_down(s, off);
        ss += __shfl_down(ss, off);
    }
    __shared__ float red[8];
    __shared__ float stats[2];
    int wvi = tid >> 6, lane = tid & 63;
    if (lane == 0) { red[wvi * 2] = s; red[wvi * 2 + 1] = ss; }
    __syncthreads();
    if (tid == 0) {
        float S = red[0] + red[2] + red[4] + red[6];
        float SS = red[1] + red[3] + red[5] + red[7];
        float mean = S * (1.f / 512.f);
        float var = SS * (1.f / 512.f) - mean * mean;
        stats[0] = mean; stats[1] = rsqrtf(var + 1e-3f);
    }
    __syncthreads();
    float mean = stats[0], rstd = stats[1];
    float o0 = (v.x - mean) * rstd * gamma[tid * 2]     + beta[tid * 2];
    float o1 = (v.y - mean) * rstd * gamma[tid * 2 + 1] + beta[tid * 2 + 1];
    unsigned w = (unsigned)f2bf(o0) | ((unsigned)f2bf(o1) << 16);
    *(unsigned*)&out[(size_t)row * 512 + tid * 2] = w;
}

// ---------------- MFMA attention: per block = 1 bh, 128 queries, 64 keys ----------------
// q_bf [bh][4096][64] bf16; kvf fp32: K at [bh][m][d], V^T at 262144 + [bh][d][m]
__global__ __launch_bounds__(256) void attn_mfma(
    const u16* __restrict__ qbf, const float* __restrict__ kvf, u16* __restrict__ attn_out)
{
    __shared__ u16 Ksh[64 * 64];      // [key][d]
    __shared__ u16 Vt[64 * 64];       // [d][key]
    __shared__ u16 Psh[4][32 * 64];   // per-wave P [qrow][key]
    const int bh = blockIdx.x, qt = blockIdx.y;
    const int tid = threadIdx.x;
    const int wv = tid >> 6, lane = tid & 63;
    const int quad = lane >> 4, l15 = lane & 15;

    {   // stage K (bf16) and V^T (bf16)
        const float* kb = kvf + (size_t)bh * 4096;
        const float* vb = kvf + 262144 + (size_t)bh * 4096;
        for (int t = tid; t < 2048; t += 256) {
            float2 a = ((const float2*)kb)[t];
            ((unsigned*)Ksh)[t] = (unsigned)f2bf(a.x) | ((unsigned)f2bf(a.y) << 16);
            float2 b2 = ((const float2*)vb)[t];
            ((unsigned*)Vt)[t] = (unsigned)f2bf(b2.x) | ((unsigned)f2bf(b2.y) << 16);
        }
    }
    __syncthreads();

    // Q fragments straight from global: rows q0+i*16+l15, d = ks*32+quad*8
    const u16* qb = qbf + ((size_t)bh * 4096 + qt * 128 + wv * 32) * 64;
    bf16x8 qf[2][2];
    #pragma unroll
    for (int i = 0; i < 2; ++i)
        #pragma unroll
        for (int ks = 0; ks < 2; ++ks)
            qf[i][ks] = *(const bf16x8*)(qb + (i * 16 + l15) * 64 + ks * 32 + quad * 8);

    // S = Q @ K^T  (contraction over d=64, two k-steps)
    floatx4 s[2][4];
    #pragma unroll
    for (int i = 0; i < 2; ++i)
        #pragma unroll
        for (int j = 0; j < 4; ++j)
            s[i][j] = (floatx4){0.f, 0.f, 0.f, 0.f};
    #pragma unroll
    for (int j = 0; j < 4; ++j) {
        #pragma unroll
        for (int ks = 0; ks < 2; ++ks) {
            bf16x8 kf = *(const bf16x8*)&Ksh[(j * 16 + l15) * 64 + ks * 32 + quad * 8];
            #pragma unroll
            for (int i = 0; i < 2; ++i)
                s[i][j] = __builtin_amdgcn_mfma_f32_16x16x32_bf16(qf[i][ks], kf, s[i][j], 0, 0, 0);
        }
    }

    // softmax (no max-shift: |s*scale| <~ 2): exp, write unnormalized P to LDS, row-sum
    u16* P = Psh[wv];
    float rs[2][4];
    #pragma unroll
    for (int i = 0; i < 2; ++i)
        #pragma unroll
        for (int r = 0; r < 4; ++r) rs[i][r] = 0.f;
    #pragma unroll
    for (int i = 0; i < 2; ++i)
        #pragma unroll
        for (int j = 0; j < 4; ++j)
            #pragma unroll
            for (int r = 0; r < 4; ++r) {
                float e = __expf(s[i][j][r] * 0.125f);
                rs[i][r] += e;
                P[(i * 16 + quad * 4 + r) * 64 + j * 16 + l15] = f2bf(e);
            }
    #pragma unroll
    for (int m = 1; m < 16; m <<= 1)
        #pragma unroll
        for (int i = 0; i < 2; ++i)
            #pragma unroll
            for (int r = 0; r < 4; ++r)
                rs[i][r] += __shfl_xor(rs[i][r], m);
    __syncthreads();   // P LDS write -> read ordering

    // O = P @ V  (contraction over keys=64, two k-steps); V^T rows are d-rows
    floatx4 o[2][4];
    #pragma unroll
    for (int i = 0; i < 2; ++i)
        #pragma unroll
        for (int j = 0; j < 4; ++j)
            o[i][j] = (floatx4){0.f, 0.f, 0.f, 0.f};
    #pragma unroll
    for (int ks = 0; ks < 2; ++ks) {
        bf16x8 pf[2];
        #pragma unroll
        for (int i = 0; i < 2; ++i)
            pf[i] = *(const bf16x8*)&P[(i * 16 + l15) * 64 + ks * 32 + quad * 8];
        #pragma unroll
        for (int j = 0; j < 4; ++j) {
            bf16x8 vf = *(const bf16x8*)&Vt[(j * 16 + l15) * 64 + ks * 32 + quad * 8];
            #pragma unroll
            for (int i = 0; i < 2; ++i)
                o[i][j] = __builtin_amdgcn_mfma_f32_16x16x32_bf16(pf[i], vf, o[i][j], 0, 0, 0);
        }
    }

    // normalize + store bf16 to [b][n][h*64+d]
    const int b = bh >> 3, h = bh & 7;
    #pragma unroll
    for (int i = 0; i < 2; ++i) {
        #pragma unroll
        for (int r = 0; r < 4; ++r) {
            float inv = 1.f / rs[i][r];
            int n = qt * 128 + wv * 32 + i * 16 + quad * 4 + r;
            u16* op = attn_out + ((size_t)(b * 4096 + n)) * 512 + h * 64;
            #pragma unroll
            for (int j = 0; j < 4; ++j)
                op[j * 16 + l15] = f2bf(o[i][j][r] * inv);
        }
    }
}

extern "C" void kernel_launch(void* const* d_in, const int* in_sizes, int n_in,
                              void* d_out, int out_size, void* d_ws, size_t ws_size,
                              hipStream_t stream) {
    const float* x      = (const float*)d_in[0];
    const float* Wq     = (const float*)d_in[1];
    const float* Wkv    = (const float*)d_in[2];
    const float* conv_w = (const float*)d_in[3];
    const float* gamma  = (const float*)d_in[4];
    const float* beta   = (const float*)d_in[5];
    const float* Wp     = (const float*)d_in[6];
    const float* bp     = (const float*)d_in[7];
    float* out = (float*)d_out;

    char* w = (char*)d_ws;
    const size_t MB = 1ull << 20;
    u16*   x_bf      = (u16*)(w + 0);           // 32 MB  [32768 x 512] bf16
    u16*   WconvT    = (u16*)(w + 32 * MB);     // 34 MB  [512 x 32832] bf16 (padded stride)
    u16*   WqTp      = (u16*)(w + 66 * MB);     // 0.5 MB [512 x 512] (head-major cols)
    u16*   WkvT      = (u16*)(w + 67 * MB);     // 1 MB   [1024 x 512]
    u16*   WpT       = (u16*)(w + 68 * MB);     // 0.5 MB [512 x 512]
    u16*   q_bf      = (u16*)(w + 69 * MB);     // 32 MB  [64][4096][64] bf16
    u16*   fmap_part = (u16*)(w + 101 * MB);    // 16 MB  [32][512 x 512] bf16
    u16*   fmap_ln   = (u16*)(w + 117 * MB);    // 0.5 MB [512 x 512] bf16
    float* kv_f      = (float*)(w + 118 * MB);  // 2 MB   K + V^T fp32
    u16*   attn_bf   = (u16*)(w + 120 * MB);    // 32 MB  [32768 x 512] bf16

    prep_kernel<<<5120, 256, 0, stream>>>(x, x_bf, conv_w, WconvT, Wq, WqTp, Wp, WpT, Wkv, WkvT);

    // conv (blocks 0..511, critical path) + q (blocks 512..1535) in one launch
    gemm_qconv<<<1536, 256, 0, stream>>>(x_bf, WconvT, fmap_part, WqTp, q_bf);

    reduce_ln_bf16<<<512, 256, 0, stream>>>(fmap_part, fmap_ln, gamma, beta);
    // kv = ln(fmap) @ Wkv -> K and V^T
    gemm_bt<2, 0><<<32, 256, 0, stream>>>(fmap_ln, WkvT, kv_f, 512, 1024, 512, 512, 512, nullptr);
    attn_mfma<<<dim3(64, 32), 256, 0, stream>>>(q_bf, kv_f, attn_bf);
    // final projection + bias
    gemm_bt<3, 0><<<1024, 256, 0, stream>>>(attn_bf, WpT, out, 32768, 512, 512, 512, 512, bp);
}

// Round 7
// 308.795 us; speedup vs baseline: 1.0320x; 1.0170x over previous
//
#include <hip/hip_runtime.h>

typedef unsigned short u16;
typedef __bf16 bf16x8 __attribute__((ext_vector_type(8)));
typedef float floatx4 __attribute__((ext_vector_type(4)));

__device__ __forceinline__ u16 f2bf(float f) {
    unsigned u = __float_as_uint(f);
    u += 0x7fff + ((u >> 16) & 1);   // round-to-nearest-even
    return (u16)(u >> 16);
}

#define GLOAD_LDS16(g, l) __builtin_amdgcn_global_load_lds( \
    (const __attribute__((address_space(1))) void*)(g),      \
    (__attribute__((address_space(3))) void*)(l), 16, 0, 0)

// WconvT row stride: 32768 + 64 u16 = 65664 B = 513 cache lines -> breaks L2 set aliasing
#define WCONV_STRIDE 32832

// ---------------- prep: conv_w transpose (dense reads) + cast x + small transposes ----------------
// blocks [0,512): conv_w transpose, tile = 64 k-rows x 512 couts.
//   Reads: 128 KB fully CONTIGUOUS per block (100% DRAM page density — the r4/r5 2 TB/s cap
//   was 256B-of-2048B strided reads). LDS [64 k][514 u16] (pitch 257 dwords -> 2-way only).
//   Writes: 128 B contiguous segments per 32 lanes.
// blocks [512,2560): cast x fp32->bf16 (2x float4 in, 1x uint4 out)
// blocks [2560,3584): Wq (head-major perm) / Wp / Wkv transposes
__global__ __launch_bounds__(256) void prep_kernel(
    const float* __restrict__ x, u16* __restrict__ x_bf,
    const float* __restrict__ conv_w, u16* __restrict__ WconvT,
    const float* __restrict__ Wq, u16* __restrict__ WqTp,
    const float* __restrict__ Wp, u16* __restrict__ WpT,
    const float* __restrict__ Wkv, u16* __restrict__ WkvT)
{
    int blk = blockIdx.x;
    const int tid = threadIdx.x;
    __shared__ __align__(16) char smem[65792];

    if (blk < 512) {
        unsigned* T32 = (unsigned*)smem;          // [64 k][257 dwords] (514 u16 pitch)
        const int k0 = blk * 64;
        #pragma unroll
        for (int it = 0; it < 32; ++it) {
            int idx = it * 256 + tid;
            int row = idx >> 7, f4 = idx & 127;   // wave: row fixed, f4 = lane -> 1 KB dense
            float4 v = *(const float4*)(conv_w + (size_t)(k0 + row) * 512 + f4 * 4);
            T32[row * 257 + f4 * 2]     = (unsigned)f2bf(v.x) | ((unsigned)f2bf(v.y) << 16);
            T32[row * 257 + f4 * 2 + 1] = (unsigned)f2bf(v.z) | ((unsigned)f2bf(v.w) << 16);
        }
        __syncthreads();
        #pragma unroll
        for (int it = 0; it < 32; ++it) {
            int u = it * 256 + tid;
            int cp = u >> 5, kp = u & 31;         // wave: kp = lane&31 -> banks 2kp%32, 2-way
            unsigned D0 = T32[kp * 514 + cp];         // k=2kp,  c={2cp,2cp+1}
            unsigned D1 = T32[kp * 514 + 257 + cp];   // k=2kp+1
            unsigned w0 = (D0 & 0xffffu) | (D1 << 16);
            unsigned w1 = (D0 >> 16) | (D1 & 0xffff0000u);
            *(unsigned*)&WconvT[(size_t)(cp * 2)     * WCONV_STRIDE + k0 + kp * 2] = w0;
            *(unsigned*)&WconvT[(size_t)(cp * 2 + 1) * WCONV_STRIDE + k0 + kp * 2] = w1;
        }
        return;
    }
    blk -= 512;

    if (blk < 2048) {
        const size_t base = (size_t)blk * 1024 + tid;   // uint4 units
        const float4* src = (const float4*)x;
        uint4* dst = (uint4*)x_bf;
        float4 a[4], b[4];
        #pragma unroll
        for (int i = 0; i < 4; ++i) {
            a[i] = src[(base + i * 256) * 2];
            b[i] = src[(base + i * 256) * 2 + 1];
        }
        #pragma unroll
        for (int i = 0; i < 4; ++i) {
            uint4 o;
            o.x = (unsigned)f2bf(a[i].x) | ((unsigned)f2bf(a[i].y) << 16);
            o.y = (unsigned)f2bf(a[i].z) | ((unsigned)f2bf(a[i].w) << 16);
            o.z = (unsigned)f2bf(b[i].x) | ((unsigned)f2bf(b[i].y) << 16);
            o.w = (unsigned)f2bf(b[i].z) | ((unsigned)f2bf(b[i].w) << 16);
            dst[base + i * 256] = o;
        }
        return;
    }
    blk -= 2048;

    const float* in; u16* outp; int R, Cn, bx, by; bool perm = false;
    if (blk < 256)      { in = Wq;  outp = WqTp; R = 512; Cn = 512;  bx = blk & 15; by = blk >> 4; perm = true; }
    else if (blk < 512) { blk -= 256; in = Wp;  outp = WpT;  R = 512; Cn = 512;  bx = blk & 15; by = blk >> 4; }
    else                { blk -= 512; in = Wkv; outp = WkvT; R = 512; Cn = 1024; bx = blk & 31; by = blk >> 5; }
    float (*tile)[33] = (float(*)[33])smem;
    const int c0 = bx * 32, r0 = by * 32;
    const int tx = tid & 31, ty = tid >> 5;
    #pragma unroll
    for (int yy = 0; yy < 4; ++yy)
        tile[ty + yy * 8][tx] = in[(size_t)(r0 + ty + yy * 8) * Cn + c0 + tx];
    __syncthreads();
    #pragma unroll
    for (int yy = 0; yy < 4; ++yy) {
        int cc = c0 + ty + yy * 8;
        int np = perm ? ((cc & 7) * 64 + (cc >> 3)) : cc;
        outp[(size_t)np * R + r0 + tx] = f2bf(tile[tx][ty + yy * 8]);
    }
}

// ---------------- MFMA GEMM body: C[M,N] = A[M,K] * B^T[N,K]  (bf16 in, fp32 acc) ----------------
// Min-2-phase pipeline: BK=32 double-buffered LDS, STAGE(t+1) before compute(t), 1 barrier/step.
// BS = B row stride (carries WconvT's L2-set-dealiasing padding).
// ASRC 0: A plain [M,K].  ASRC 1: A rows are conv patches gathered from x_bf.
// MODE 0: split-K partial bf16 store   MODE 1: q permuted store
// MODE 2: kv permute -> bf16 (K + V^T) MODE 3: out + bias fp32
template<int MODE, int ASRC>
__device__ __forceinline__ void gemm_body(
    const u16* __restrict__ A, const u16* __restrict__ B, float* __restrict__ out,
    int M, int N, int K, int BS, int KC, const float* __restrict__ bias,
    int id, int zz, u16 (*As)[4096], u16 (*Bs)[4096])
{
    const int tid = threadIdx.x;
    const int wv = tid >> 6, lane = tid & 63;
    const int quad = lane >> 4, l15 = lane & 15;
    constexpr int GX = (MODE == 2) ? 8 : 4;
    const int bm = (id / GX) * 128, bn = (id % GX) * 128;
    const int k0 = zz * KC;
    const int wr = wv >> 1, wc = wv & 1;

    floatx4 acc[4][4];
    #pragma unroll
    for (int i = 0; i < 4; ++i)
        #pragma unroll
        for (int j = 0; j < 4; ++j)
            acc[i][j] = (floatx4){0.f, 0.f, 0.f, 0.f};

    auto stage = [&](int step, int buf) {
        const int kk = k0 + (step << 5);
        #pragma unroll
        for (int c2 = 0; c2 < 2; ++c2) {
            const int chunk = wv * 2 + c2;
            const int idx = (chunk * 64 + lane) * 8;   // element offset in [128][32]
            const int row = idx >> 5, col = idx & 31;
            const int k = kk + col;
            if (ASRC == 0) {
                GLOAD_LDS16(A + (size_t)(bm + row) * K + k, &As[buf][chunk * 512]);
            } else {
                int p = bm + row;
                int b = p >> 6, ij = p & 63, ii = ij >> 3, jj = ij & 7;
                int r12 = k >> 9, r1 = r12 >> 3, r2 = r12 & 7;
                int n = (ii * 8 + r1) * 64 + jj * 8 + r2;
                GLOAD_LDS16(A + ((size_t)(b * 4096 + n)) * 512 + (k & 511), &As[buf][chunk * 512]);
            }
            GLOAD_LDS16(B + (size_t)(bn + row) * BS + k, &Bs[buf][chunk * 512]);
        }
    };
    auto compute = [&](int buf) {
        bf16x8 af[4], bfr[4];
        #pragma unroll
        for (int i = 0; i < 4; ++i)
            af[i] = *(const bf16x8*)&As[buf][(wr * 64 + i * 16 + l15) * 32 + quad * 8];
        #pragma unroll
        for (int j = 0; j < 4; ++j)
            bfr[j] = *(const bf16x8*)&Bs[buf][(wc * 64 + j * 16 + l15) * 32 + quad * 8];
        #pragma unroll
        for (int i = 0; i < 4; ++i)
            #pragma unroll
            for (int j = 0; j < 4; ++j)
                acc[i][j] = __builtin_amdgcn_mfma_f32_16x16x32_bf16(af[i], bfr[j], acc[i][j], 0, 0, 0);
    };

    const int nsteps = KC >> 5;          // always even (KC multiple of 64)
    stage(0, 0);
    __syncthreads();
    for (int step = 0; step < nsteps; step += 2) {
        stage(step + 1, 1);
        compute(0);
        __syncthreads();
        if (step + 2 < nsteps) stage(step + 2, 0);
        compute(1);
        __syncthreads();
    }

    #pragma unroll
    for (int i = 0; i < 4; ++i) {
        #pragma unroll
        for (int j = 0; j < 4; ++j) {
            #pragma unroll
            for (int r = 0; r < 4; ++r) {
                int m = bm + wr * 64 + i * 16 + quad * 4 + r;
                int n = bn + wc * 64 + j * 16 + l15;
                float v = acc[i][j][r];
                if (MODE == 0) {
                    ((u16*)out)[(size_t)zz * 262144 + (size_t)m * N + n] = f2bf(v);
                } else if (MODE == 1) {
                    int b = m >> 12, nn = m & 4095;
                    int h = n >> 6, d = n & 63;     // B columns pre-permuted head-major
                    ((u16*)out)[((size_t)((b * 8 + h) * 4096 + nn)) * 64 + d] = f2bf(v);
                } else if (MODE == 2) {
                    int b = m >> 6, mm = m & 63;
                    int f = n >> 9, c = n & 511, h = c >> 6, d = c & 63;
                    size_t idx;
                    if (f == 0) idx = ((size_t)((b * 8 + h) * 64 + mm)) * 64 + d;
                    else        idx = 262144 + ((size_t)((b * 8 + h) * 64 + d)) * 64 + mm;  // V^T
                    ((u16*)out)[idx] = f2bf(v);    // bf16 kv (same rounding attn applied before)
                } else {
                    out[(size_t)m * 512 + n] = v + bias[n];
                }
            }
        }
    }
}

// thin wrapper: 1-D flat grid, XCD-chunked swizzle for non-split-K modes
template<int MODE, int ASRC>
__global__ __launch_bounds__(256) void gemm_bt(
    const u16* __restrict__ A, const u16* __restrict__ B, float* __restrict__ out,
    int M, int N, int K, int BS, int KC, const float* __restrict__ bias)
{
    __shared__ u16 As[2][4096], Bs[2][4096];
    int id = blockIdx.x;
    if (MODE != 0) {
        const int nwg = gridDim.x;       // divisible by 8 for all uses
        id = (id & 7) * (nwg >> 3) + (id >> 3);
    }
    gemm_body<MODE, ASRC>(A, B, out, M, N, K, BS, KC, bias, id, blockIdx.z, As, Bs);
}

// merged q-GEMM + conv-GEMM.
// conv blocks [0,512): z-chunked XCD swizzle — each XCD gets 4 complete z-slices (16 blocks
// sharing A/B panels, ~1.5 MB, fits one L2) -> panel re-reads become L2 hits.
__global__ __launch_bounds__(256) void gemm_qconv(
    const u16* __restrict__ x_bf, const u16* __restrict__ WconvT, u16* __restrict__ fmap_part,
    const u16* __restrict__ WqTp, u16* __restrict__ q_bf)
{
    __shared__ u16 As[2][4096], Bs[2][4096];
    const int blk = blockIdx.x;
    if (blk < 512) {
        const int L = (blk & 7) * 64 + (blk >> 3);   // bijective: XCD k owns L in [64k, 64k+64)
        gemm_body<0, 1>(x_bf, WconvT, (float*)fmap_part, 512, 512, 32768, WCONV_STRIDE, 1024,
                        nullptr, L & 15, L >> 4, As, Bs);
    } else {
        int id = blk - 512;                      // 0..1023
        id = (id & 7) * 128 + (id >> 3);         // XCD-chunked swizzle, nwg=1024
        gemm_body<1, 0>(x_bf, WqTp, (float*)q_bf, 32768, 512, 512, 512, 512,
                        nullptr, id, 0, As, Bs);
    }
}

// ---------------- split-K reduce (32 bf16 slices) + LayerNorm over C=512, output bf16 ----------------
__global__ __launch_bounds__(256) void reduce_ln_bf16(
    const u16* __restrict__ part, u16* __restrict__ out,
    const float* __restrict__ gamma, const float* __restrict__ beta)
{
    int row = blockIdx.x, tid = threadIdx.x;
    const unsigned* base = (const unsigned*)(part + (size_t)row * 512) + tid;
    float2 v = {0.f, 0.f};
    #pragma unroll 8
    for (int z = 0; z < 32; ++z) {
        unsigned u = base[(size_t)z * 131072];   // 262144 u16 = 131072 dwords per slice
        v.x += __uint_as_float(u << 16);
        v.y += __uint_as_float(u & 0xffff0000u);
    }
    float s = v.x + v.y, ss = v.x * v.x + v.y * v.y;
    #pragma unroll
    for (int off = 32; off > 0; off >>= 1) {
        s  += __shfl_down(s, off);
        ss += __shfl_down(ss, off);
    }
    __shared__ float red[8];
    __shared__ float stats[2];
    int wvi = tid >> 6, lane = tid & 63;
    if (lane == 0) { red[wvi * 2] = s; red[wvi * 2 + 1] = ss; }
    __syncthreads();
    if (tid == 0) {
        float S = red[0] + red[2] + red[4] + red[6];
        float SS = red[1] + red[3] + red[5] + red[7];
        float mean = S * (1.f / 512.f);
        float var = SS * (1.f / 512.f) - mean * mean;
        stats[0] = mean; stats[1] = rsqrtf(var + 1e-3f);
    }
    __syncthreads();
    float mean = stats[0], rstd = stats[1];
    float o0 = (v.x - mean) * rstd * gamma[tid * 2]     + beta[tid * 2];
    float o1 = (v.y - mean) * rstd * gamma[tid * 2 + 1] + beta[tid * 2 + 1];
    unsigned w = (unsigned)f2bf(o0) | ((unsigned)f2bf(o1) << 16);
    *(unsigned*)&out[(size_t)row * 512 + tid * 2] = w;
}

// ---------------- MFMA attention: per block = 1 bh, 128 queries, 64 keys ----------------
// q_bf [bh][4096][64] bf16; kvb bf16: K at [bh][m][d], V^T at 262144 + [bh][d][m]
__global__ __launch_bounds__(256) void attn_mfma(
    const u16* __restrict__ qbf, const u16* __restrict__ kvb, u16* __restrict__ attn_out)
{
    __shared__ u16 Ksh[64 * 64];      // [key][d]
    __shared__ u16 Vt[64 * 64];       // [d][key]
    __shared__ u16 Psh[4][32 * 64];   // per-wave P [qrow][key]
    const int bh = blockIdx.x, qt = blockIdx.y;
    const int tid = threadIdx.x;
    const int wv = tid >> 6, lane = tid & 63;
    const int quad = lane >> 4, l15 = lane & 15;

    {   // stage K and V^T (already bf16: plain dword copies)
        const unsigned* kb = (const unsigned*)(kvb + (size_t)bh * 4096);
        const unsigned* vb = (const unsigned*)(kvb + 262144 + (size_t)bh * 4096);
        #pragma unroll
        for (int t = tid; t < 2048; t += 256) {
            ((unsigned*)Ksh)[t] = kb[t];
            ((unsigned*)Vt)[t]  = vb[t];
        }
    }
    __syncthreads();

    // Q fragments straight from global: rows q0+i*16+l15, d = ks*32+quad*8
    const u16* qb = qbf + ((size_t)bh * 4096 + qt * 128 + wv * 32) * 64;
    bf16x8 qf[2][2];
    #pragma unroll
    for (int i = 0; i < 2; ++i)
        #pragma unroll
        for (int ks = 0; ks < 2; ++ks)
            qf[i][ks] = *(const bf16x8*)(qb + (i * 16 + l15) * 64 + ks * 32 + quad * 8);

    // S = Q @ K^T  (contraction over d=64, two k-steps)
    floatx4 s[2][4];
    #pragma unroll
    for (int i = 0; i < 2; ++i)
        #pragma unroll
        for (int j = 0; j < 4; ++j)
            s[i][j] = (floatx4){0.f, 0.f, 0.f, 0.f};
    #pragma unroll
    for (int j = 0; j < 4; ++j) {
        #pragma unroll
        for (int ks = 0; ks < 2; ++ks) {
            bf16x8 kf = *(const bf16x8*)&Ksh[(j * 16 + l15) * 64 + ks * 32 + quad * 8];
            #pragma unroll
            for (int i = 0; i < 2; ++i)
                s[i][j] = __builtin_amdgcn_mfma_f32_16x16x32_bf16(qf[i][ks], kf, s[i][j], 0, 0, 0);
        }
    }

    // softmax (no max-shift: |s*scale| <~ 2): exp, write unnormalized P to LDS, row-sum
    u16* P = Psh[wv];
    float rs[2][4];
    #pragma unroll
    for (int i = 0; i < 2; ++i)
        #pragma unroll
        for (int r = 0; r < 4; ++r) rs[i][r] = 0.f;
    #pragma unroll
    for (int i = 0; i < 2; ++i)
        #pragma unroll
        for (int j = 0; j < 4; ++j)
            #pragma unroll
            for (int r = 0; r < 4; ++r) {
                float e = __expf(s[i][j][r] * 0.125f);
                rs[i][r] += e;
                P[(i * 16 + quad * 4 + r) * 64 + j * 16 + l15] = f2bf(e);
            }
    #pragma unroll
    for (int m = 1; m < 16; m <<= 1)
        #pragma unroll
        for (int i = 0; i < 2; ++i)
            #pragma unroll
            for (int r = 0; r < 4; ++r)
                rs[i][r] += __shfl_xor(rs[i][r], m);
    __syncthreads();   // P LDS write -> read ordering

    // O = P @ V  (contraction over keys=64, two k-steps); V^T rows are d-rows
    floatx4 o[2][4];
    #pragma unroll
    for (int i = 0; i < 2; ++i)
        #pragma unroll
        for (int j = 0; j < 4; ++j)
            o[i][j] = (floatx4){0.f, 0.f, 0.f, 0.f};
    #pragma unroll
    for (int ks = 0; ks < 2; ++ks) {
        bf16x8 pf[2];
        #pragma unroll
        for (int i = 0; i < 2; ++i)
            pf[i] = *(const bf16x8*)&P[(i * 16 + l15) * 64 + ks * 32 + quad * 8];
        #pragma unroll
        for (int j = 0; j < 4; ++j) {
            bf16x8 vf = *(const bf16x8*)&Vt[(j * 16 + l15) * 64 + ks * 32 + quad * 8];
            #pragma unroll
            for (int i = 0; i < 2; ++i)
                o[i][j] = __builtin_amdgcn_mfma_f32_16x16x32_bf16(pf[i], vf, o[i][j], 0, 0, 0);
        }
    }

    // normalize + store bf16 to [b][n][h*64+d]
    const int b = bh >> 3, h = bh & 7;
    #pragma unroll
    for (int i = 0; i < 2; ++i) {
        #pragma unroll
        for (int r = 0; r < 4; ++r) {
            float inv = 1.f / rs[i][r];
            int n = qt * 128 + wv * 32 + i * 16 + quad * 4 + r;
            u16* op = attn_out + ((size_t)(b * 4096 + n)) * 512 + h * 64;
            #pragma unroll
            for (int j = 0; j < 4; ++j)
                op[j * 16 + l15] = f2bf(o[i][j][r] * inv);
        }
    }
}

extern "C" void kernel_launch(void* const* d_in, const int* in_sizes, int n_in,
                              void* d_out, int out_size, void* d_ws, size_t ws_size,
                              hipStream_t stream) {
    const float* x      = (const float*)d_in[0];
    const float* Wq     = (const float*)d_in[1];
    const float* Wkv    = (const float*)d_in[2];
    const float* conv_w = (const float*)d_in[3];
    const float* gamma  = (const float*)d_in[4];
    const float* beta   = (const float*)d_in[5];
    const float* Wp     = (const float*)d_in[6];
    const float* bp     = (const float*)d_in[7];
    float* out = (float*)d_out;

    char* w = (char*)d_ws;
    const size_t MB = 1ull << 20;
    u16*   x_bf      = (u16*)(w + 0);           // 32 MB  [32768 x 512] bf16
    u16*   WconvT    = (u16*)(w + 32 * MB);     // 34 MB  [512 x 32832] bf16 (padded stride)
    u16*   WqTp      = (u16*)(w + 66 * MB);     // 0.5 MB [512 x 512] (head-major cols)
    u16*   WkvT      = (u16*)(w + 67 * MB);     // 1 MB   [1024 x 512]
    u16*   WpT       = (u16*)(w + 68 * MB);     // 0.5 MB [512 x 512]
    u16*   q_bf      = (u16*)(w + 69 * MB);     // 32 MB  [64][4096][64] bf16
    u16*   fmap_part = (u16*)(w + 101 * MB);    // 16 MB  [32][512 x 512] bf16
    u16*   fmap_ln   = (u16*)(w + 117 * MB);    // 0.5 MB [512 x 512] bf16
    u16*   kv_bf     = (u16*)(w + 118 * MB);    // 1 MB   K + V^T bf16
    u16*   attn_bf   = (u16*)(w + 120 * MB);    // 32 MB  [32768 x 512] bf16

    prep_kernel<<<3584, 256, 0, stream>>>(x, x_bf, conv_w, WconvT, Wq, WqTp, Wp, WpT, Wkv, WkvT);

    // conv (blocks 0..511, z-chunked per XCD) + q (blocks 512..1535) in one launch
    gemm_qconv<<<1536, 256, 0, stream>>>(x_bf, WconvT, fmap_part, WqTp, q_bf);

    reduce_ln_bf16<<<512, 256, 0, stream>>>(fmap_part, fmap_ln, gamma, beta);
    // kv = ln(fmap) @ Wkv -> K and V^T, stored bf16
    gemm_bt<2, 0><<<32, 256, 0, stream>>>(fmap_ln, WkvT, (float*)kv_bf, 512, 1024, 512, 512, 512, nullptr);
    attn_mfma<<<dim3(64, 32), 256, 0, stream>>>(q_bf, kv_bf, attn_bf);
    // final projection + bias
    gemm_bt<3, 0><<<1024, 256, 0, stream>>>(attn_bf, WpT, out, 32768, 512, 512, 512, 512, bp);
}

// Round 8
// 308.515 us; speedup vs baseline: 1.0329x; 1.0009x over previous
//
#include <hip/hip_runtime.h>

typedef unsigned short u16;
typedef __bf16 bf16x8 __attribute__((ext_vector_type(8)));
typedef float floatx4 __attribute__((ext_vector_type(4)));

__device__ __forceinline__ u16 f2bf(float f) {
    unsigned u = __float_as_uint(f);
    u += 0x7fff + ((u >> 16) & 1);   // round-to-nearest-even
    return (u16)(u >> 16);
}

#define GLOAD_LDS16(g, l) __builtin_amdgcn_global_load_lds( \
    (const __attribute__((address_space(1))) void*)(g),      \
    (__attribute__((address_space(3))) void*)(l), 16, 0, 0)

// WconvT row stride: 32768 + 64 u16 = 65664 B = 513 cache lines -> breaks L2 set aliasing
#define WCONV_STRIDE 32832

// ---------------- prep: conv_w transpose (dense reads) + cast x + small transposes ----------------
__global__ __launch_bounds__(256) void prep_kernel(
    const float* __restrict__ x, u16* __restrict__ x_bf,
    const float* __restrict__ conv_w, u16* __restrict__ WconvT,
    const float* __restrict__ Wq, u16* __restrict__ WqTp,
    const float* __restrict__ Wp, u16* __restrict__ WpT,
    const float* __restrict__ Wkv, u16* __restrict__ WkvT)
{
    int blk = blockIdx.x;
    const int tid = threadIdx.x;
    __shared__ __align__(16) char smem[65792];

    if (blk < 512) {
        unsigned* T32 = (unsigned*)smem;          // [64 k][257 dwords] (514 u16 pitch)
        const int k0 = blk * 64;
        #pragma unroll
        for (int it = 0; it < 32; ++it) {
            int idx = it * 256 + tid;
            int row = idx >> 7, f4 = idx & 127;   // wave: row fixed, f4 = lane -> 1 KB dense
            float4 v = *(const float4*)(conv_w + (size_t)(k0 + row) * 512 + f4 * 4);
            T32[row * 257 + f4 * 2]     = (unsigned)f2bf(v.x) | ((unsigned)f2bf(v.y) << 16);
            T32[row * 257 + f4 * 2 + 1] = (unsigned)f2bf(v.z) | ((unsigned)f2bf(v.w) << 16);
        }
        __syncthreads();
        #pragma unroll
        for (int it = 0; it < 32; ++it) {
            int u = it * 256 + tid;
            int cp = u >> 5, kp = u & 31;
            unsigned D0 = T32[kp * 514 + cp];         // k=2kp,  c={2cp,2cp+1}
            unsigned D1 = T32[kp * 514 + 257 + cp];   // k=2kp+1
            unsigned w0 = (D0 & 0xffffu) | (D1 << 16);
            unsigned w1 = (D0 >> 16) | (D1 & 0xffff0000u);
            *(unsigned*)&WconvT[(size_t)(cp * 2)     * WCONV_STRIDE + k0 + kp * 2] = w0;
            *(unsigned*)&WconvT[(size_t)(cp * 2 + 1) * WCONV_STRIDE + k0 + kp * 2] = w1;
        }
        return;
    }
    blk -= 512;

    if (blk < 2048) {
        const size_t base = (size_t)blk * 1024 + tid;   // uint4 units
        const float4* src = (const float4*)x;
        uint4* dst = (uint4*)x_bf;
        float4 a[4], b[4];
        #pragma unroll
        for (int i = 0; i < 4; ++i) {
            a[i] = src[(base + i * 256) * 2];
            b[i] = src[(base + i * 256) * 2 + 1];
        }
        #pragma unroll
        for (int i = 0; i < 4; ++i) {
            uint4 o;
            o.x = (unsigned)f2bf(a[i].x) | ((unsigned)f2bf(a[i].y) << 16);
            o.y = (unsigned)f2bf(a[i].z) | ((unsigned)f2bf(a[i].w) << 16);
            o.z = (unsigned)f2bf(b[i].x) | ((unsigned)f2bf(b[i].y) << 16);
            o.w = (unsigned)f2bf(b[i].z) | ((unsigned)f2bf(b[i].w) << 16);
            dst[base + i * 256] = o;
        }
        return;
    }
    blk -= 2048;

    const float* in; u16* outp; int R, Cn, bx, by; bool perm = false;
    if (blk < 256)      { in = Wq;  outp = WqTp; R = 512; Cn = 512;  bx = blk & 15; by = blk >> 4; perm = true; }
    else if (blk < 512) { blk -= 256; in = Wp;  outp = WpT;  R = 512; Cn = 512;  bx = blk & 15; by = blk >> 4; }
    else                { blk -= 512; in = Wkv; outp = WkvT; R = 512; Cn = 1024; bx = blk & 31; by = blk >> 5; }
    float (*tile)[33] = (float(*)[33])smem;
    const int c0 = bx * 32, r0 = by * 32;
    const int tx = tid & 31, ty = tid >> 5;
    #pragma unroll
    for (int yy = 0; yy < 4; ++yy)
        tile[ty + yy * 8][tx] = in[(size_t)(r0 + ty + yy * 8) * Cn + c0 + tx];
    __syncthreads();
    #pragma unroll
    for (int yy = 0; yy < 4; ++yy) {
        int cc = c0 + ty + yy * 8;
        int np = perm ? ((cc & 7) * 64 + (cc >> 3)) : cc;
        outp[(size_t)np * R + r0 + tx] = f2bf(tile[tx][ty + yy * 8]);
    }
}

// ---------------- MFMA GEMM body: C[M,N] = A[M,K] * B^T[N,K]  (bf16 in, fp32 acc) ----------------
// Min-2-phase pipeline: BK=32 double-buffered LDS, STAGE(t+1) before compute(t), 1 barrier/step.
// Epilogue: per-wave LDS transpose (reusing As/Bs, dead after last barrier) -> wide stores:
//   MODE 0/1: uint2 per lane, 16 lanes/row = 128 B contiguous segments
//   MODE 3:   float4 per lane + bias, 16 lanes/row = 256 B contiguous segments
//   MODE 2:   scalar (tiny)
template<int MODE, int ASRC>
__device__ __forceinline__ void gemm_body(
    const u16* __restrict__ A, const u16* __restrict__ B, float* __restrict__ out,
    int M, int N, int K, int BS, int KC, const float* __restrict__ bias,
    int id, int zz, u16 (*As)[4096], u16 (*Bs)[4096])
{
    const int tid = threadIdx.x;
    const int wv = tid >> 6, lane = tid & 63;
    const int quad = lane >> 4, l15 = lane & 15;
    constexpr int GX = (MODE == 2) ? 8 : 4;
    const int bm = (id / GX) * 128, bn = (id % GX) * 128;
    const int k0 = zz * KC;
    const int wr = wv >> 1, wc = wv & 1;

    floatx4 acc[4][4];
    #pragma unroll
    for (int i = 0; i < 4; ++i)
        #pragma unroll
        for (int j = 0; j < 4; ++j)
            acc[i][j] = (floatx4){0.f, 0.f, 0.f, 0.f};

    auto stage = [&](int step, int buf) {
        const int kk = k0 + (step << 5);
        #pragma unroll
        for (int c2 = 0; c2 < 2; ++c2) {
            const int chunk = wv * 2 + c2;
            const int idx = (chunk * 64 + lane) * 8;   // element offset in [128][32]
            const int row = idx >> 5, col = idx & 31;
            const int k = kk + col;
            if (ASRC == 0) {
                GLOAD_LDS16(A + (size_t)(bm + row) * K + k, &As[buf][chunk * 512]);
            } else {
                int p = bm + row;
                int b = p >> 6, ij = p & 63, ii = ij >> 3, jj = ij & 7;
                int r12 = k >> 9, r1 = r12 >> 3, r2 = r12 & 7;
                int n = (ii * 8 + r1) * 64 + jj * 8 + r2;
                GLOAD_LDS16(A + ((size_t)(b * 4096 + n)) * 512 + (k & 511), &As[buf][chunk * 512]);
            }
            GLOAD_LDS16(B + (size_t)(bn + row) * BS + k, &Bs[buf][chunk * 512]);
        }
    };
    auto compute = [&](int buf) {
        bf16x8 af[4], bfr[4];
        #pragma unroll
        for (int i = 0; i < 4; ++i)
            af[i] = *(const bf16x8*)&As[buf][(wr * 64 + i * 16 + l15) * 32 + quad * 8];
        #pragma unroll
        for (int j = 0; j < 4; ++j)
            bfr[j] = *(const bf16x8*)&Bs[buf][(wc * 64 + j * 16 + l15) * 32 + quad * 8];
        #pragma unroll
        for (int i = 0; i < 4; ++i)
            #pragma unroll
            for (int j = 0; j < 4; ++j)
                acc[i][j] = __builtin_amdgcn_mfma_f32_16x16x32_bf16(af[i], bfr[j], acc[i][j], 0, 0, 0);
    };

    const int nsteps = KC >> 5;          // always even (KC multiple of 64)
    stage(0, 0);
    __syncthreads();
    for (int step = 0; step < nsteps; step += 2) {
        stage(step + 1, 1);
        compute(0);
        __syncthreads();
        if (step + 2 < nsteps) stage(step + 2, 0);
        compute(1);
        __syncthreads();
    }
    // after final barrier all waves are done with As/Bs -> reuse as per-wave epilogue scratch

    const int lr = lane >> 4, lc = lane & 15;
    if (MODE == 2) {
        #pragma unroll
        for (int i = 0; i < 4; ++i)
            #pragma unroll
            for (int j = 0; j < 4; ++j)
                #pragma unroll
                for (int r = 0; r < 4; ++r) {
                    int m = bm + wr * 64 + i * 16 + quad * 4 + r;
                    int n = bn + wc * 64 + j * 16 + l15;
                    int b = m >> 6, mm = m & 63;
                    int f = n >> 9, c = n & 511, h = c >> 6, d = c & 63;
                    size_t idx;
                    if (f == 0) idx = ((size_t)((b * 8 + h) * 64 + mm)) * 64 + d;
                    else        idx = 262144 + ((size_t)((b * 8 + h) * 64 + d)) * 64 + mm;  // V^T
                    ((u16*)out)[idx] = f2bf(acc[i][j][r]);
                }
    } else if (MODE == 3) {
        // per-wave fp32 scratch [16][68] (4352 B): waves 0,1 in As; 2,3 in Bs
        float* W = (float*)(wv < 2 ? (void*)As : (void*)Bs) + (wv & 1) * (16 * 68);
        #pragma unroll
        for (int i = 0; i < 4; ++i) {
            #pragma unroll
            for (int j = 0; j < 4; ++j)
                #pragma unroll
                for (int r = 0; r < 4; ++r)
                    W[(quad * 4 + r) * 68 + j * 16 + l15] = acc[i][j][r];
            __asm__ volatile("" ::: "memory");   // order LDS write->read (per-wave, in-order DS pipe)
            #pragma unroll
            for (int t = 0; t < 4; ++t) {
                int mrow = lr + t * 4;
                float4 v = *(const float4*)&W[mrow * 68 + lc * 4];
                int m = bm + wr * 64 + i * 16 + mrow;
                int n = bn + wc * 64 + lc * 4;
                float4 bv = *(const float4*)&bias[n];
                v.x += bv.x; v.y += bv.y; v.z += bv.z; v.w += bv.w;
                *(float4*)&out[(size_t)m * 512 + n] = v;   // 16 lanes = 256 B row
            }
            __asm__ volatile("" ::: "memory");
        }
    } else {
        // per-wave bf16 scratch [16][68] u16 (2176 B)
        u16* W = (u16*)(wv < 2 ? (void*)As : (void*)Bs) + (wv & 1) * (16 * 68);
        #pragma unroll
        for (int i = 0; i < 4; ++i) {
            #pragma unroll
            for (int j = 0; j < 4; ++j)
                #pragma unroll
                for (int r = 0; r < 4; ++r)
                    W[(quad * 4 + r) * 68 + j * 16 + l15] = f2bf(acc[i][j][r]);
            __asm__ volatile("" ::: "memory");
            #pragma unroll
            for (int t = 0; t < 4; ++t) {
                int mrow = lr + t * 4;
                uint2 v = *(const uint2*)&W[mrow * 68 + lc * 4];
                int m = bm + wr * 64 + i * 16 + mrow;
                int nb = bn + wc * 64 + lc * 4;           // 4 consecutive n
                if (MODE == 0) {
                    *(uint2*)&((u16*)out)[(size_t)zz * 262144 + (size_t)m * N + nb] = v;
                } else {   // MODE 1: wave's 64-n range = exactly one head
                    int b = m >> 12, nn = m & 4095;
                    int h = nb >> 6, d = nb & 63;
                    *(uint2*)&((u16*)out)[((size_t)((b * 8 + h) * 4096 + nn)) * 64 + d] = v;
                }
            }
            __asm__ volatile("" ::: "memory");
        }
    }
}

// thin wrapper: 1-D flat grid, XCD-chunked swizzle for non-split-K modes
template<int MODE, int ASRC>
__global__ __launch_bounds__(256) void gemm_bt(
    const u16* __restrict__ A, const u16* __restrict__ B, float* __restrict__ out,
    int M, int N, int K, int BS, int KC, const float* __restrict__ bias)
{
    __shared__ u16 As[2][4096], Bs[2][4096];
    int id = blockIdx.x;
    if (MODE != 0) {
        const int nwg = gridDim.x;       // divisible by 8 for all uses
        id = (id & 7) * (nwg >> 3) + (id >> 3);
    }
    gemm_body<MODE, ASRC>(A, B, out, M, N, K, BS, KC, bias, id, blockIdx.z, As, Bs);
}

// merged q-GEMM + conv-GEMM; conv blocks z-chunked per XCD (panel re-reads hit L2)
__global__ __launch_bounds__(256) void gemm_qconv(
    const u16* __restrict__ x_bf, const u16* __restrict__ WconvT, u16* __restrict__ fmap_part,
    const u16* __restrict__ WqTp, u16* __restrict__ q_bf)
{
    __shared__ u16 As[2][4096], Bs[2][4096];
    const int blk = blockIdx.x;
    if (blk < 512) {
        const int L = (blk & 7) * 64 + (blk >> 3);   // bijective: XCD k owns L in [64k, 64k+64)
        gemm_body<0, 1>(x_bf, WconvT, (float*)fmap_part, 512, 512, 32768, WCONV_STRIDE, 1024,
                        nullptr, L & 15, L >> 4, As, Bs);
    } else {
        int id = blk - 512;                      // 0..1023
        id = (id & 7) * 128 + (id >> 3);         // XCD-chunked swizzle, nwg=1024
        gemm_body<1, 0>(x_bf, WqTp, (float*)q_bf, 32768, 512, 512, 512, 512,
                        nullptr, id, 0, As, Bs);
    }
}

// ---------------- split-K reduce (32 bf16 slices) + LayerNorm over C=512, output bf16 ----------------
__global__ __launch_bounds__(256) void reduce_ln_bf16(
    const u16* __restrict__ part, u16* __restrict__ out,
    const float* __restrict__ gamma, const float* __restrict__ beta)
{
    int row = blockIdx.x, tid = threadIdx.x;
    const unsigned* base = (const unsigned*)(part + (size_t)row * 512) + tid;
    float2 v = {0.f, 0.f};
    #pragma unroll 8
    for (int z = 0; z < 32; ++z) {
        unsigned u = base[(size_t)z * 131072];   // 262144 u16 = 131072 dwords per slice
        v.x += __uint_as_float(u << 16);
        v.y += __uint_as_float(u & 0xffff0000u);
    }
    float s = v.x + v.y, ss = v.x * v.x + v.y * v.y;
    #pragma unroll
    for (int off = 32; off > 0; off >>= 1) {
        s  += __shfl_down(s, off);
        ss += __shfl_down(ss, off);
    }
    __shared__ float red[8];
    __shared__ float stats[2];
    int wvi = tid >> 6, lane = tid & 63;
    if (lane == 0) { red[wvi * 2] = s; red[wvi * 2 + 1] = ss; }
    __syncthreads();
    if (tid == 0) {
        float S = red[0] + red[2] + red[4] + red[6];
        float SS = red[1] + red[3] + red[5] + red[7];
        float mean = S * (1.f / 512.f);
        float var = SS * (1.f / 512.f) - mean * mean;
        stats[0] = mean; stats[1] = rsqrtf(var + 1e-3f);
    }
    __syncthreads();
    float mean = stats[0], rstd = stats[1];
    float o0 = (v.x - mean) * rstd * gamma[tid * 2]     + beta[tid * 2];
    float o1 = (v.y - mean) * rstd * gamma[tid * 2 + 1] + beta[tid * 2 + 1];
    unsigned w = (unsigned)f2bf(o0) | ((unsigned)f2bf(o1) << 16);
    *(unsigned*)&out[(size_t)row * 512 + tid * 2] = w;
}

// ---------------- MFMA attention: per block = 1 bh, 128 queries, 64 keys ----------------
// q_bf [bh][4096][64] bf16; kvb bf16: K at [bh][m][d], V^T at 262144 + [bh][d][m]
__global__ __launch_bounds__(256) void attn_mfma(
    const u16* __restrict__ qbf, const u16* __restrict__ kvb, u16* __restrict__ attn_out)
{
    __shared__ u16 Ksh[64 * 64];      // [key][d]
    __shared__ u16 Vt[64 * 64];       // [d][key]
    __shared__ u16 Psh[4][32 * 64];   // per-wave P [qrow][key]; reused as epilogue scratch
    const int bh = blockIdx.x, qt = blockIdx.y;
    const int tid = threadIdx.x;
    const int wv = tid >> 6, lane = tid & 63;
    const int quad = lane >> 4, l15 = lane & 15;

    {   // stage K and V^T (already bf16: plain dword copies)
        const unsigned* kb = (const unsigned*)(kvb + (size_t)bh * 4096);
        const unsigned* vb = (const unsigned*)(kvb + 262144 + (size_t)bh * 4096);
        #pragma unroll
        for (int t = tid; t < 2048; t += 256) {
            ((unsigned*)Ksh)[t] = kb[t];
            ((unsigned*)Vt)[t]  = vb[t];
        }
    }
    __syncthreads();

    const u16* qb = qbf + ((size_t)bh * 4096 + qt * 128 + wv * 32) * 64;
    bf16x8 qf[2][2];
    #pragma unroll
    for (int i = 0; i < 2; ++i)
        #pragma unroll
        for (int ks = 0; ks < 2; ++ks)
            qf[i][ks] = *(const bf16x8*)(qb + (i * 16 + l15) * 64 + ks * 32 + quad * 8);

    floatx4 s[2][4];
    #pragma unroll
    for (int i = 0; i < 2; ++i)
        #pragma unroll
        for (int j = 0; j < 4; ++j)
            s[i][j] = (floatx4){0.f, 0.f, 0.f, 0.f};
    #pragma unroll
    for (int j = 0; j < 4; ++j) {
        #pragma unroll
        for (int ks = 0; ks < 2; ++ks) {
            bf16x8 kf = *(const bf16x8*)&Ksh[(j * 16 + l15) * 64 + ks * 32 + quad * 8];
            #pragma unroll
            for (int i = 0; i < 2; ++i)
                s[i][j] = __builtin_amdgcn_mfma_f32_16x16x32_bf16(qf[i][ks], kf, s[i][j], 0, 0, 0);
        }
    }

    // softmax (no max-shift: |s*scale| <~ 2): exp, write unnormalized P to LDS, row-sum
    u16* P = Psh[wv];
    float rs[2][4];
    #pragma unroll
    for (int i = 0; i < 2; ++i)
        #pragma unroll
        for (int r = 0; r < 4; ++r) rs[i][r] = 0.f;
    #pragma unroll
    for (int i = 0; i < 2; ++i)
        #pragma unroll
        for (int j = 0; j < 4; ++j)
            #pragma unroll
            for (int r = 0; r < 4; ++r) {
                float e = __expf(s[i][j][r] * 0.125f);
                rs[i][r] += e;
                P[(i * 16 + quad * 4 + r) * 64 + j * 16 + l15] = f2bf(e);
            }
    #pragma unroll
    for (int m = 1; m < 16; m <<= 1)
        #pragma unroll
        for (int i = 0; i < 2; ++i)
            #pragma unroll
            for (int r = 0; r < 4; ++r)
                rs[i][r] += __shfl_xor(rs[i][r], m);
    __syncthreads();   // P LDS write -> read ordering

    floatx4 o[2][4];
    #pragma unroll
    for (int i = 0; i < 2; ++i)
        #pragma unroll
        for (int j = 0; j < 4; ++j)
            o[i][j] = (floatx4){0.f, 0.f, 0.f, 0.f};
    #pragma unroll
    for (int ks = 0; ks < 2; ++ks) {
        bf16x8 pf[2];
        #pragma unroll
        for (int i = 0; i < 2; ++i)
            pf[i] = *(const bf16x8*)&P[(i * 16 + l15) * 64 + ks * 32 + quad * 8];
        #pragma unroll
        for (int j = 0; j < 4; ++j) {
            bf16x8 vf = *(const bf16x8*)&Vt[(j * 16 + l15) * 64 + ks * 32 + quad * 8];
            #pragma unroll
            for (int i = 0; i < 2; ++i)
                o[i][j] = __builtin_amdgcn_mfma_f32_16x16x32_bf16(pf[i], vf, o[i][j], 0, 0, 0);
        }
    }

    // epilogue: normalize -> per-wave [32 q][64 d] bf16 in Psh[wv] (P is dead), wide store
    const int b = bh >> 3, h = bh & 7;
    #pragma unroll
    for (int i = 0; i < 2; ++i)
        #pragma unroll
        for (int r = 0; r < 4; ++r) {
            float inv = 1.f / rs[i][r];
            #pragma unroll
            for (int j = 0; j < 4; ++j)
                P[(i * 16 + quad * 4 + r) * 64 + j * 16 + l15] = f2bf(o[i][j][r] * inv);
        }
    __asm__ volatile("" ::: "memory");   // per-wave LDS write->read ordering
    const int lr = lane >> 4, lc = lane & 15;
    #pragma unroll
    for (int t = 0; t < 8; ++t) {
        int row = lr + t * 4;
        uint2 v = *(const uint2*)&P[row * 64 + lc * 4];
        int n = qt * 128 + wv * 32 + row;
        // 16 lanes cover one 128 B contiguous row segment
        *(uint2*)&attn_out[((size_t)(b * 4096 + n)) * 512 + h * 64 + lc * 4] = v;
    }
}

extern "C" void kernel_launch(void* const* d_in, const int* in_sizes, int n_in,
                              void* d_out, int out_size, void* d_ws, size_t ws_size,
                              hipStream_t stream) {
    const float* x      = (const float*)d_in[0];
    const float* Wq     = (const float*)d_in[1];
    const float* Wkv    = (const float*)d_in[2];
    const float* conv_w = (const float*)d_in[3];
    const float* gamma  = (const float*)d_in[4];
    const float* beta   = (const float*)d_in[5];
    const float* Wp     = (const float*)d_in[6];
    const float* bp     = (const float*)d_in[7];
    float* out = (float*)d_out;

    char* w = (char*)d_ws;
    const size_t MB = 1ull << 20;
    u16*   x_bf      = (u16*)(w + 0);           // 32 MB  [32768 x 512] bf16
    u16*   WconvT    = (u16*)(w + 32 * MB);     // 34 MB  [512 x 32832] bf16 (padded stride)
    u16*   WqTp      = (u16*)(w + 66 * MB);     // 0.5 MB [512 x 512] (head-major cols)
    u16*   WkvT      = (u16*)(w + 67 * MB);     // 1 MB   [1024 x 512]
    u16*   WpT       = (u16*)(w + 68 * MB);     // 0.5 MB [512 x 512]
    u16*   q_bf      = (u16*)(w + 69 * MB);     // 32 MB  [64][4096][64] bf16
    u16*   fmap_part = (u16*)(w + 101 * MB);    // 16 MB  [32][512 x 512] bf16
    u16*   fmap_ln   = (u16*)(w + 117 * MB);    // 0.5 MB [512 x 512] bf16
    u16*   kv_bf     = (u16*)(w + 118 * MB);    // 1 MB   K + V^T bf16
    u16*   attn_bf   = (u16*)(w + 120 * MB);    // 32 MB  [32768 x 512] bf16

    prep_kernel<<<3584, 256, 0, stream>>>(x, x_bf, conv_w, WconvT, Wq, WqTp, Wp, WpT, Wkv, WkvT);

    // conv (blocks 0..511, z-chunked per XCD) + q (blocks 512..1535) in one launch
    gemm_qconv<<<1536, 256, 0, stream>>>(x_bf, WconvT, fmap_part, WqTp, q_bf);

    reduce_ln_bf16<<<512, 256, 0, stream>>>(fmap_part, fmap_ln, gamma, beta);
    // kv = ln(fmap) @ Wkv -> K and V^T, stored bf16
    gemm_bt<2, 0><<<32, 256, 0, stream>>>(fmap_ln, WkvT, (float*)kv_bf, 512, 1024, 512, 512, 512, nullptr);
    attn_mfma<<<dim3(64, 32), 256, 0, stream>>>(q_bf, kv_bf, attn_bf);
    // final projection + bias
    gemm_bt<3, 0><<<1024, 256, 0, stream>>>(attn_bf, WpT, out, 32768, 512, 512, 512, 512, bp);
}